// Round 1
// baseline (1640.110 us; speedup 1.0000x reference)
//
#include <hip/hip_runtime.h>

typedef unsigned short u16;
typedef unsigned int   u32;
typedef short s8v __attribute__((ext_vector_type(8)));   // 8 x bf16 (4 VGPR) MFMA operand
typedef float f4v __attribute__((ext_vector_type(4)));   // MFMA accumulator

#define DEV __device__ __forceinline__

DEV u16 f2b(float f){                      // f32 -> bf16, round-to-nearest-even
  u32 x = __builtin_bit_cast(u32, f);
  u32 r = x + 0x7fffu + ((x >> 16) & 1u);
  return (u16)(r >> 16);
}
DEV float b2f(u16 u){ u32 x = ((u32)u) << 16; return __builtin_bit_cast(float, x); }
DEV f4v mfma16(s8v a, s8v b, f4v c){ return __builtin_amdgcn_mfma_f32_16x16x32_bf16(a, b, c, 0, 0, 0); }

// ---------------- init: seg_start boundaries + vr-region bias init ----------------
__global__ __launch_bounds__(256) void k_init(const int* __restrict__ im_idx, const float* __restrict__ b_vr,
                                              int P, int B, int* __restrict__ seg_start, float* __restrict__ px){
  int idx = blockIdx.x*256 + threadIdx.x;
  if (idx < B*512) px[(idx>>9)*1536 + 1024 + (idx&511)] = b_vr[idx&511];
  if (idx < P){
    int b = im_idx[idx];
    if (idx == 0) seg_start[b] = 0;
    else if (im_idx[idx-1] != b) seg_start[b] = idx;
  }
  if (idx == 0) seg_start[B] = P;
}

// ---------------- weight transforms ----------------
__global__ __launch_bounds__(256) void k_w1t(const float* __restrict__ w_c1, u16* __restrict__ w1t){
  int i = blockIdx.x*256 + threadIdx.x;                  // [128 oc][128 k]
  if (i >= 128*128) return;
  int k = i & 127;
  w1t[i] = f2b(k < 98 ? w_c1[(i>>7)*98 + k] : 0.f);
}
__global__ __launch_bounds__(256) void k_w2t(const float* __restrict__ w_c2, u16* __restrict__ w2t){
  int i = blockIdx.x*256 + threadIdx.x;                  // [9 tap][256 oc][128 ic]
  if (i >= 9*256*128) return;
  int tap = i >> 15; int r = i & 32767;
  int oc = r >> 7, ic = r & 127;
  w2t[i] = f2b(w_c2[(oc*128 + ic)*9 + tap]);
}
__global__ __launch_bounds__(256) void k_cvt_bf(const float* __restrict__ src, u16* __restrict__ dst, int n){
  int i = blockIdx.x*256 + threadIdx.x;
  if (i < n) dst[i] = f2b(src[i]);
}
__global__ __launch_bounds__(256) void k_transpose_bf(const float* __restrict__ src, u16* __restrict__ dst,
                                                      int R, int C){
  __shared__ float tile[64][65];
  int r0 = blockIdx.x << 6, c0 = blockIdx.y << 6;
  for (int i = threadIdx.x; i < 4096; i += 256){
    int rl = i >> 6, cl = i & 63;
    tile[rl][cl] = src[(size_t)(r0+rl)*C + c0 + cl];
  }
  __syncthreads();
  for (int i = threadIdx.x; i < 4096; i += 256){
    int cl = i >> 6, rl = i & 63;
    dst[(size_t)(c0+cl)*R + r0 + rl] = f2b(tile[rl][cl]);
  }
}

// ---------------- segment-mean of union_feat -> mu_T[b][49 pix][1024 ic] bf16 ----------------
__global__ __launch_bounds__(256) void k_union_pool(const float* __restrict__ uf, const int* __restrict__ seg,
                                                    u16* __restrict__ mu_T){
  int b = blockIdx.x, icb = blockIdx.y, t = threadIdx.x;  // icb: 16 chunks of 64 ic
  int s0 = seg[b], s1 = seg[b+1];
  float inv = 1.f / fmaxf((float)(s1 - s0), 1.f);
  f4v a0 = {}, a1 = {}, a2 = {}, a3 = {};
  for (int p = s0; p < s1; ++p){
    const f4v* src = (const f4v*)(uf + (size_t)p*50176 + icb*3136);
    a0 += src[t]; a1 += src[t+256]; a2 += src[t+512];
    if (t + 768 < 784) a3 += src[t+768];
  }
  __shared__ float lds[3136];                             // [64 ic][49 pix]
  *(f4v*)&lds[4*t] = a0;
  *(f4v*)&lds[4*(t+256)] = a1;
  *(f4v*)&lds[4*(t+512)] = a2;
  if (t + 768 < 784) *(f4v*)&lds[4*(t+768)] = a3;
  __syncthreads();
  for (int o = t; o < 3136; o += 256){
    int pix = o >> 6, ics = o & 63;
    mu_T[(size_t)(b*49 + pix)*1024 + (icb<<6) + ics] = f2b(lds[ics*49 + pix]*inv);
  }
}

// ---------------- segment-mean of gathered features -> pf[b][2][2048] f32 ----------------
__global__ __launch_bounds__(256) void k_feat_pool(const float* __restrict__ feat, const int* __restrict__ pidx,
                                                   const int* __restrict__ seg, float* __restrict__ pf){
  int b = blockIdx.x, s = blockIdx.y, t = threadIdx.x;
  int s0 = seg[b], s1 = seg[b+1];
  float inv = 1.f / fmaxf((float)(s1 - s0), 1.f);
  f4v a0 = {}, a1 = {};
  for (int p = s0; p < s1; ++p){
    int row = pidx[p*2 + s];
    const f4v* src = (const f4v*)(feat + (size_t)row*2048);
    a0 += src[t]; a1 += src[t+256];
  }
  f4v* dst = (f4v*)(pf + (size_t)(b*2 + s)*2048);
  dst[t] = a0*inv; dst[t+256] = a1*inv;
}

// ---------------- conv1 (7x7 s2 p3, 2->128) via im2col-in-LDS MFMA ----------------
// MODE 0: relu -> per-channel sum/sumsq (BN1 stats). MODE 1: relu -> bn1 -> maxpool3 s2 p1 -> spool[p][49][128] bf16
template<int MODE>
__global__ __launch_bounds__(256) void k_conv1(const float* __restrict__ masks, const u16* __restrict__ w1t,
                                               const float* __restrict__ b1,
                                               const float* __restrict__ scale1, const float* __restrict__ shift1,
                                               float* __restrict__ stats1, u16* __restrict__ spool){
  __shared__ float in_lds[2178];    // [2][33][33] zero-padded input
  __shared__ u16 a2col[28288];      // [208 m][136 k] bf16; reused as s1n[128][196] in MODE 1
  int p = blockIdx.x, t = threadIdx.x;
  int lane = t & 63, w = t >> 6;
  int l15 = lane & 15, lhi = lane >> 4;
  {
    f4v z = {}; f4v* a4 = (f4v*)a2col;
    for (int i = t; i < 3536; i += 256) a4[i] = z;
    for (int i = t; i < 2178; i += 256) in_lds[i] = 0.f;
  }
  __syncthreads();
  for (int e = t; e < 1458; e += 256){
    int c = e / 729, r = e - c*729;
    in_lds[c*1089 + (r/27 + 3)*33 + (r%27 + 3)] = masks[(size_t)p*1458 + e];
  }
  __syncthreads();
  for (int e = t; e < 19208; e += 256){                   // im2col: A[pix][k], k = ic*49+ky*7+kx
    int pix = e / 98, k = e - pix*98;
    int ic = k / 49, r = k - ic*49;
    int ky = r / 7, kx = r - ky*7;
    int oy = pix / 14, ox = pix - oy*14;
    a2col[pix*136 + k] = f2b(in_lds[ic*1089 + (oy*2 + ky)*33 + (ox*2 + kx)]);
  }
  __syncthreads();
  f4v acc[13][2] = {};
  int ocb = w*32;
  for (int kst = 0; kst < 4; ++kst){
    int koff = kst*32 + lhi*8;
    s8v B0 = *(const s8v*)&w1t[(ocb + l15)*128 + koff];
    s8v B1 = *(const s8v*)&w1t[(ocb + 16 + l15)*128 + koff];
    #pragma unroll
    for (int mt = 0; mt < 13; ++mt){
      s8v A = *(const s8v*)&a2col[(mt*16 + l15)*136 + koff];
      acc[mt][0] = mfma16(A, B0, acc[mt][0]);
      acc[mt][1] = mfma16(A, B1, acc[mt][1]);
    }
  }
  __syncthreads();
  if (MODE == 0){
    #pragma unroll
    for (int n = 0; n < 2; ++n){
      float bias = b1[ocb + n*16 + l15];
      float s = 0.f, q = 0.f;
      #pragma unroll
      for (int mt = 0; mt < 13; ++mt)
        #pragma unroll
        for (int v = 0; v < 4; ++v){
          int pix = mt*16 + lhi*4 + v;
          float r = fmaxf(acc[mt][n][v] + bias, 0.f);
          if (pix < 196){ s += r; q += r*r; }
        }
      s += __shfl_xor(s, 16); s += __shfl_xor(s, 32);
      q += __shfl_xor(q, 16); q += __shfl_xor(q, 32);
      if (lane < 16){
        atomicAdd(&stats1[ocb + n*16 + lane], s);
        atomicAdd(&stats1[128 + ocb + n*16 + lane], q);
      }
    }
  } else {
    u16* s1n = a2col;                                     // [128 oc][196 pix] bf16 (post-BN)
    #pragma unroll
    for (int n = 0; n < 2; ++n){
      int oc = ocb + n*16 + l15;
      float bias = b1[oc], sc = scale1[oc], sh = shift1[oc];
      #pragma unroll
      for (int mt = 0; mt < 13; ++mt)
        #pragma unroll
        for (int v = 0; v < 4; ++v){
          int pix = mt*16 + lhi*4 + v;
          if (pix < 196){
            float r = fmaxf(acc[mt][n][v] + bias, 0.f);
            s1n[oc*196 + pix] = f2b(r*sc + sh);
          }
        }
    }
    __syncthreads();
    for (int j = t; j < 6272; j += 256){                  // maxpool 3x3 s2 p1 on 14x14 -> 7x7
      int oc = j & 127, pp = j >> 7;
      int poy = pp / 7, pox = pp - poy*7;
      float m = -3.4e38f;
      #pragma unroll
      for (int dy = 0; dy < 3; ++dy){
        int iy = poy*2 - 1 + dy;
        if (iy < 0 || iy > 13) continue;
        #pragma unroll
        for (int dx = 0; dx < 3; ++dx){
          int ix = pox*2 - 1 + dx;
          if (ix < 0 || ix > 13) continue;
          m = fmaxf(m, b2f(s1n[oc*196 + iy*14 + ix]));
        }
      }
      spool[((size_t)p*49 + pp)*128 + oc] = f2b(m);
    }
  }
}

// ---------------- conv2 (3x3 s1 p1, 128->256) 9-tap MFMA; relu -> segment sums + BN2 stats ----------------
__global__ __launch_bounds__(256) void k_conv2(const u16* __restrict__ spool, const u16* __restrict__ w2t,
                                               const float* __restrict__ b2, const int* __restrict__ seg,
                                               float* __restrict__ segr, float* __restrict__ stats2){
  __shared__ u16 inT[82*136];        // [9x9 padded pixel][128 ic] bf16, row 81 = zeros (M-pad)
  int b = blockIdx.x, q = blockIdx.y, t = threadIdx.x;
  int lane = t & 63, w = t >> 6;
  int l15 = lane & 15, lhi = lane >> 4;
  int s0 = seg[b], s1 = seg[b+1];
  int cnt = s1 - s0;
  int chunk = (cnt + 4) / 5;
  int p0 = s0 + q*chunk;
  int p1 = min(p0 + chunk, s1);
  {
    f4v z = {}; f4v* a4 = (f4v*)inT;
    for (int i = t; i < 1394; i += 256) a4[i] = z;
  }
  f4v segacc[4][4] = {};
  float ssum[4] = {0,0,0,0}, ssq[4] = {0,0,0,0};
  int ocb = w*64;
  int moy[4], mox[4]; bool mok[4];
  #pragma unroll
  for (int mt = 0; mt < 4; ++mt){
    int m = mt*16 + l15;
    moy[mt] = m / 7; mox[mt] = m - moy[mt]*7; mok[mt] = (m < 49);
  }
  for (int p = p0; p < p1; ++p){
    __syncthreads();
    const u32* src = (const u32*)(spool + (size_t)p*6272);
    u32* dT = (u32*)inT;
    for (int i = t; i < 3136; i += 256){
      int pix = i >> 6, icp = i & 63;
      int py = pix / 7;
      dT[((py + 1)*9 + (pix - py*7) + 1)*68 + icp] = src[i];
    }
    __syncthreads();
    f4v pacc[4][4] = {};
    for (int tap = 0; tap < 9; ++tap){
      int ky = tap / 3;
      int dy = ky - 1, dx = tap - ky*3 - 1;
      int rowb[4];
      #pragma unroll
      for (int mt = 0; mt < 4; ++mt)
        rowb[mt] = mok[mt] ? ((moy[mt] + 1 + dy)*9 + mox[mt] + 1 + dx)*136 : 81*136;
      for (int kst = 0; kst < 4; ++kst){
        int koff = kst*32 + lhi*8;
        s8v Bf[4];
        #pragma unroll
        for (int nt = 0; nt < 4; ++nt)
          Bf[nt] = *(const s8v*)&w2t[(tap*256 + ocb + nt*16 + l15)*128 + koff];
        #pragma unroll
        for (int mt = 0; mt < 4; ++mt){
          s8v A = *(const s8v*)&inT[rowb[mt] + koff];
          #pragma unroll
          for (int nt = 0; nt < 4; ++nt)
            pacc[mt][nt] = mfma16(A, Bf[nt], pacc[mt][nt]);
        }
      }
    }
    #pragma unroll
    for (int nt = 0; nt < 4; ++nt){
      float bias = b2[ocb + nt*16 + l15];
      #pragma unroll
      for (int mt = 0; mt < 4; ++mt)
        #pragma unroll
        for (int v = 0; v < 4; ++v){
          int pix = mt*16 + lhi*4 + v;
          float r = fmaxf(pacc[mt][nt][v] + bias, 0.f);
          r = (pix < 49) ? r : 0.f;
          segacc[mt][nt][v] += r;
          ssum[nt] += r; ssq[nt] += r*r;
        }
    }
  }
  #pragma unroll
  for (int nt = 0; nt < 4; ++nt){
    int oc = ocb + nt*16 + l15;
    #pragma unroll
    for (int mt = 0; mt < 4; ++mt)
      #pragma unroll
      for (int v = 0; v < 4; ++v){
        int pix = mt*16 + lhi*4 + v;
        if (pix < 49)
          atomicAdd(&segr[(size_t)(b*256 + oc)*49 + pix], segacc[mt][nt][v]);
      }
    float s = ssum[nt], qq = ssq[nt];
    s += __shfl_xor(s, 16); s += __shfl_xor(s, 32);
    qq += __shfl_xor(qq, 16); qq += __shfl_xor(qq, 32);
    if (lane < 16){
      atomicAdd(&stats2[ocb + nt*16 + lane], s);
      atomicAdd(&stats2[256 + ocb + nt*16 + lane], qq);
    }
  }
}

// ---------------- BN finalize: stats -> scale/shift ----------------
__global__ __launch_bounds__(256) void k_bnfin(const float* __restrict__ stats, const float* __restrict__ g,
                                               const float* __restrict__ be, float* __restrict__ scale,
                                               float* __restrict__ shift, int C, float invN){
  int c = threadIdx.x;
  if (c < C){
    float mean = stats[c]*invN;
    float var  = stats[C + c]*invN - mean*mean;
    float sc = g[c]*rsqrtf(var + 1e-5f);
    scale[c] = sc;
    shift[c] = be[c] - mean*sc;
  }
}

// ---------------- combine: u_pool (1x1 conv of pooled union) + bn2(seg mean relu2) -> t_bf[b][12544] bf16 ----------------
__global__ __launch_bounds__(256) void k_combine(const u16* __restrict__ mu_T, const u16* __restrict__ w_uT,
                                                 const float* __restrict__ b_u, const float* __restrict__ segr,
                                                 const float* __restrict__ scale2, const float* __restrict__ shift2,
                                                 const int* __restrict__ seg, const u16* __restrict__ zp,
                                                 u16* __restrict__ t_bf){
  int b = blockIdx.x, t = threadIdx.x;
  int lane = t & 63, w = t >> 6;
  int l15 = lane & 15, lhi = lane >> 4;
  float inv = 1.f / fmaxf((float)(seg[b+1] - seg[b]), 1.f);
  int ocb = w*64;
  const u16* arow[4];
  #pragma unroll
  for (int mt = 0; mt < 4; ++mt){
    int pix = mt*16 + l15;
    arow[mt] = (pix < 49) ? (mu_T + (size_t)(b*49 + pix)*1024) : zp;
  }
  f4v acc[4][4] = {};
  for (int kst = 0; kst < 32; ++kst){
    int koff = kst*32 + lhi*8;
    s8v Bf[4];
    #pragma unroll
    for (int nt = 0; nt < 4; ++nt)
      Bf[nt] = *(const s8v*)&w_uT[(ocb + nt*16 + l15)*1024 + koff];
    #pragma unroll
    for (int mt = 0; mt < 4; ++mt){
      s8v A = *(const s8v*)&arow[mt][koff];
      #pragma unroll
      for (int nt = 0; nt < 4; ++nt)
        acc[mt][nt] = mfma16(A, Bf[nt], acc[mt][nt]);
    }
  }
  #pragma unroll
  for (int nt = 0; nt < 4; ++nt){
    int oc = ocb + nt*16 + l15;
    float bu = b_u[oc], sc = scale2[oc], sh = shift2[oc];
    #pragma unroll
    for (int mt = 0; mt < 4; ++mt)
      #pragma unroll
      for (int v = 0; v < 4; ++v){
        int pix = mt*16 + lhi*4 + v;
        if (pix < 49){
          float val = acc[mt][nt][v] + bu + sc*segr[(size_t)(b*256 + oc)*49 + pix]*inv + sh;
          t_bf[(size_t)b*12544 + oc*49 + pix] = f2b(val);
        }
      }
  }
}

// ---------------- vr GEMM: [112,12544]@[12544,512], k-split, atomic into pooled_x cols 1024.. ----------------
__global__ __launch_bounds__(256) void k_vr(const u16* __restrict__ t_bf, const u16* __restrict__ wvrT,
                                            float* __restrict__ px, int B){
  int nb = blockIdx.x, kc = blockIdx.y, t = threadIdx.x;
  int lane = t & 63, w = t >> 6;
  int l15 = lane & 15, lhi = lane >> 4;
  int colb = nb*256 + w*64;
  int k0 = kc*896;
  f4v acc[7][4] = {};
  for (int kst = 0; kst < 28; ++kst){
    int koff = k0 + kst*32 + lhi*8;
    s8v Bf[4];
    #pragma unroll
    for (int nt = 0; nt < 4; ++nt)
      Bf[nt] = *(const s8v*)&wvrT[(size_t)(colb + nt*16 + l15)*12544 + koff];
    #pragma unroll
    for (int mt = 0; mt < 7; ++mt){
      s8v A = *(const s8v*)&t_bf[(size_t)(mt*16 + l15)*12544 + koff];
      #pragma unroll
      for (int nt = 0; nt < 4; ++nt)
        acc[mt][nt] = mfma16(A, Bf[nt], acc[mt][nt]);
    }
  }
  #pragma unroll
  for (int nt = 0; nt < 4; ++nt){
    int col = colb + nt*16 + l15;
    #pragma unroll
    for (int mt = 0; mt < 7; ++mt)
      #pragma unroll
      for (int v = 0; v < 4; ++v){
        int row = mt*16 + lhi*4 + v;
        if (row < B) atomicAdd(&px[row*1536 + 1024 + col], acc[mt][nt][v]);
      }
  }
}

// ---------------- subj/obj heads on pooled features (vector f32) ----------------
__global__ __launch_bounds__(256) void k_subjobj(const float* __restrict__ pf, const float* __restrict__ w_subj,
                                                 const float* __restrict__ b_subj, const float* __restrict__ w_obj,
                                                 const float* __restrict__ b_obj, float* __restrict__ px){
  int b = blockIdx.x, ch = blockIdx.y;
  int s = ch >> 1, col = ((ch & 1) << 8) + threadIdx.x;
  const float* W = s ? w_obj : w_subj;
  const float* bias = s ? b_obj : b_subj;
  const float* pv = pf + (size_t)(b*2 + s)*2048;
  float acc = bias[col];
  for (int k = 0; k < 2048; ++k)
    acc += pv[k]*W[k*512 + col];
  px[b*1536 + s*512 + col] = acc;
}

// ---------------- MLP head m1 (MFMA) ----------------
__global__ __launch_bounds__(256) void k_m1(const u16* __restrict__ pbf, const u16* __restrict__ wm1T,
                                            const float* __restrict__ b_m1, float* __restrict__ h, int B){
  int nb = blockIdx.x, t = threadIdx.x;
  int lane = t & 63, w = t >> 6;
  int l15 = lane & 15, lhi = lane >> 4;
  int colb = nb*256 + w*64;
  f4v acc[7][4] = {};
  for (int kst = 0; kst < 48; ++kst){
    int koff = kst*32 + lhi*8;
    s8v Bf[4];
    #pragma unroll
    for (int nt = 0; nt < 4; ++nt)
      Bf[nt] = *(const s8v*)&wm1T[(size_t)(colb + nt*16 + l15)*1536 + koff];
    #pragma unroll
    for (int mt = 0; mt < 7; ++mt){
      s8v A = *(const s8v*)&pbf[(mt*16 + l15)*1536 + koff];
      #pragma unroll
      for (int nt = 0; nt < 4; ++nt)
        acc[mt][nt] = mfma16(A, Bf[nt], acc[mt][nt]);
    }
  }
  #pragma unroll
  for (int nt = 0; nt < 4; ++nt){
    int col = colb + nt*16 + l15;
    float bias = b_m1[col];
    #pragma unroll
    for (int mt = 0; mt < 7; ++mt)
      #pragma unroll
      for (int v = 0; v < 4; ++v){
        int row = mt*16 + lhi*4 + v;
        if (row < B) h[row*2048 + col] = fmaxf(acc[mt][nt][v] + bias, 0.f);
      }
  }
}

// ---------------- MLP head m2 + sigmoid -> out ----------------
__global__ __launch_bounds__(192) void k_m2(const float* __restrict__ h, const float* __restrict__ w_m2,
                                            const float* __restrict__ b_m2, float* __restrict__ out){
  int b = blockIdx.x, col = threadIdx.x;
  if (col >= 157) return;
  float acc = b_m2[col];
  const float* hb = h + (size_t)b*2048;
  for (int k = 0; k < 2048; ++k)
    acc += hb[k]*w_m2[k*157 + col];
  out[b*157 + col] = 1.f/(1.f + expf(-acc));
}

extern "C" void kernel_launch(void* const* d_in, const int* in_sizes, int n_in,
                              void* d_out, int out_size, void* d_ws, size_t ws_size,
                              hipStream_t stream){
  const float* features   = (const float*)d_in[0];
  const float* union_feat = (const float*)d_in[1];
  const float* masks      = (const float*)d_in[2];
  const float* w_union    = (const float*)d_in[3];
  const float* b_union    = (const float*)d_in[4];
  const float* w_c1       = (const float*)d_in[5];
  const float* b_c1       = (const float*)d_in[6];
  const float* g_bn1      = (const float*)d_in[7];
  const float* be_bn1     = (const float*)d_in[8];
  const float* w_c2       = (const float*)d_in[9];
  const float* b_c2       = (const float*)d_in[10];
  const float* g_bn2      = (const float*)d_in[11];
  const float* be_bn2     = (const float*)d_in[12];
  const float* w_subj     = (const float*)d_in[13];
  const float* b_subj     = (const float*)d_in[14];
  const float* w_obj      = (const float*)d_in[15];
  const float* b_obj      = (const float*)d_in[16];
  const float* w_vr       = (const float*)d_in[17];
  const float* b_vr       = (const float*)d_in[18];
  const float* w_m1       = (const float*)d_in[19];
  const float* b_m1       = (const float*)d_in[20];
  const float* w_m2       = (const float*)d_in[21];
  const float* b_m2       = (const float*)d_in[22];
  const int* pair_idx     = (const int*)d_in[23];
  const int* im_idx       = (const int*)d_in[24];
  float* out = (float*)d_out;
  const int P = in_sizes[24];
  const int B = out_size/157;

  char* ws = (char*)d_ws;
  size_t off = 0;
  auto alloc = [&](size_t bytes)->size_t{ size_t o = off; off += (bytes + 255) & ~(size_t)255; return o; };
  size_t o_muT  = alloc((size_t)B*49*1024*2);
  size_t o_spool= alloc((size_t)P*49*128*2);
  size_t o_w1t  = alloc(128*128*2);
  size_t o_w2t  = alloc(9*256*128*2);
  size_t o_wuT  = alloc(256*1024*2);
  size_t o_wvrT = alloc((size_t)512*12544*2);
  size_t o_wm1T = alloc((size_t)2048*1536*2);
  size_t o_pf   = alloc((size_t)B*2*2048*4);
  size_t o_stats= alloc(3072);
  size_t o_sc1  = alloc(1024);
  size_t o_sc2  = alloc(2048);
  size_t o_seg  = alloc(512);
  size_t o_segr = alloc((size_t)B*256*49*4);
  size_t o_tbf  = alloc((size_t)112*12544*2);
  size_t o_px   = alloc((size_t)B*1536*4);
  size_t o_pbf  = alloc((size_t)112*1536*2);
  size_t o_h    = alloc((size_t)B*2048*4);
  size_t o_zp   = alloc(4096);
  (void)ws_size; (void)n_in;

  float* stats1 = (float*)(ws + o_stats);
  float* stats2 = stats1 + 256;
  float* scale1 = (float*)(ws + o_sc1);
  float* shift1 = scale1 + 128;
  float* scale2 = (float*)(ws + o_sc2);
  float* shift2 = scale2 + 256;
  int*   seg    = (int*)(ws + o_seg);
  u16*   muT    = (u16*)(ws + o_muT);
  u16*   spool  = (u16*)(ws + o_spool);
  u16*   w1t    = (u16*)(ws + o_w1t);
  u16*   w2t    = (u16*)(ws + o_w2t);
  u16*   wuT    = (u16*)(ws + o_wuT);
  u16*   wvrT   = (u16*)(ws + o_wvrT);
  u16*   wm1T   = (u16*)(ws + o_wm1T);
  float* pf     = (float*)(ws + o_pf);
  float* segr   = (float*)(ws + o_segr);
  u16*   tbf    = (u16*)(ws + o_tbf);
  float* px     = (float*)(ws + o_px);
  u16*   pbf    = (u16*)(ws + o_pbf);
  float* h      = (float*)(ws + o_h);
  u16*   zp     = (u16*)(ws + o_zp);

  hipMemsetAsync(ws + o_stats, 0, 3072, stream);
  hipMemsetAsync(ws + o_segr, 0, (size_t)B*256*49*4, stream);
  hipMemsetAsync(ws + o_tbf, 0, (size_t)112*12544*2, stream);
  hipMemsetAsync(ws + o_pbf, 0, (size_t)112*1536*2, stream);
  hipMemsetAsync(ws + o_zp, 0, 4096, stream);

  dim3 blk(256);
  int g_init = ((B*512 > P ? B*512 : P) + 255)/256;
  k_init<<<g_init, blk, 0, stream>>>(im_idx, b_vr, P, B, seg, px);
  k_w1t<<<64, blk, 0, stream>>>(w_c1, w1t);
  k_w2t<<<1152, blk, 0, stream>>>(w_c2, w2t);
  k_cvt_bf<<<1024, blk, 0, stream>>>(w_union, wuT, 256*1024);
  k_transpose_bf<<<dim3(196, 8), blk, 0, stream>>>(w_vr, wvrT, 12544, 512);
  k_transpose_bf<<<dim3(24, 32), blk, 0, stream>>>(w_m1, wm1T, 1536, 2048);
  k_union_pool<<<dim3(B, 16), blk, 0, stream>>>(union_feat, seg, muT);
  k_feat_pool<<<dim3(B, 2), blk, 0, stream>>>(features, pair_idx, seg, pf);
  k_conv1<0><<<P, blk, 0, stream>>>(masks, w1t, b_c1, nullptr, nullptr, stats1, nullptr);
  k_bnfin<<<1, blk, 0, stream>>>(stats1, g_bn1, be_bn1, scale1, shift1, 128, 1.f/((float)P*196.f));
  k_conv1<1><<<P, blk, 0, stream>>>(masks, w1t, b_c1, scale1, shift1, nullptr, spool);
  k_conv2<<<dim3(B, 5), blk, 0, stream>>>(spool, w2t, b_c2, seg, segr, stats2);
  k_bnfin<<<1, blk, 0, stream>>>(stats2, g_bn2, be_bn2, scale2, shift2, 256, 1.f/((float)P*49.f));
  k_combine<<<B, blk, 0, stream>>>(muT, wuT, b_union, segr, scale2, shift2, seg, zp, tbf);
  k_vr<<<dim3(2, 14), blk, 0, stream>>>(tbf, wvrT, px, B);
  k_subjobj<<<dim3(B, 4), blk, 0, stream>>>(pf, w_subj, b_subj, w_obj, b_obj, px);
  k_cvt_bf<<<(B*1536 + 255)/256, blk, 0, stream>>>(px, pbf, B*1536);
  k_m1<<<8, blk, 0, stream>>>(pbf, wm1T, b_m1, h, B);
  k_m2<<<B, dim3(192), 0, stream>>>(h, w_m2, b_m2, out);
}

// Round 2
// 1448.336 us; speedup vs baseline: 1.1324x; 1.1324x over previous
//
#include <hip/hip_runtime.h>

typedef unsigned short u16;
typedef unsigned int   u32;
typedef short s8v __attribute__((ext_vector_type(8)));   // 8 x bf16 (4 VGPR) MFMA operand
typedef float f4v __attribute__((ext_vector_type(4)));   // MFMA accumulator

#define DEV __device__ __forceinline__

DEV u16 f2b(float f){                      // f32 -> bf16, round-to-nearest-even
  u32 x = __builtin_bit_cast(u32, f);
  u32 r = x + 0x7fffu + ((x >> 16) & 1u);
  return (u16)(r >> 16);
}
DEV float b2f(u16 u){ u32 x = ((u32)u) << 16; return __builtin_bit_cast(float, x); }
DEV f4v mfma16(s8v a, s8v b, f4v c){ return __builtin_amdgcn_mfma_f32_16x16x32_bf16(a, b, c, 0, 0, 0); }

// binary-search segment [s0,s1) of image b in sorted im_idx (removes k_init dependency)
DEV void segrange(const int* __restrict__ im, int P, int b, int& s0, int& s1){
  int lo = 0, hi = P;
  while (lo < hi){ int m = (lo + hi) >> 1; if (im[m] < b) lo = m + 1; else hi = m; }
  s0 = lo;
  int lo2 = lo; hi = P;
  while (lo2 < hi){ int m = (lo2 + hi) >> 1; if (im[m] < b + 1) lo2 = m + 1; else hi = m; }
  s1 = lo2;
}

DEV void transpose_body(const float* __restrict__ src, u16* __restrict__ dst,
                        int R, int C, int rb, int cb, int t, float* tile){
  int r0 = rb << 6, c0 = cb << 6;
  for (int i = t; i < 4096; i += 256){
    int rl = i >> 6, cl = i & 63;
    tile[rl*65 + cl] = src[(size_t)(r0 + rl)*C + c0 + cl];
  }
  __syncthreads();
  for (int i = t; i < 4096; i += 256){
    int cl = i >> 6, rl = i & 63;
    dst[(size_t)(c0 + cl)*R + r0 + rl] = f2b(tile[rl*65 + cl]);
  }
}

// ================= k_pre: ALL input-only work fused (overlaps under union_pool's HBM floor) ========
// blocks [0,1600): union segment-mean -> muT[b][49][1024] bf16
// blocks [1600,1800): feature segment-mean + subj/obj GEMV -> px cols [0,1024)
// blocks [1800,1864): w1t   [64,1864+1152): w2t   [3016..): wuT cvt   [4040..): wvrT   [5608..): wm1T
__global__ __launch_bounds__(256) void k_pre(
    const float* __restrict__ uf, const float* __restrict__ feat,
    const int* __restrict__ pidx, const int* __restrict__ im_idx,
    const float* __restrict__ w_c1, const float* __restrict__ w_c2, const float* __restrict__ w_u,
    const float* __restrict__ w_vr, const float* __restrict__ w_m1,
    const float* __restrict__ w_subj, const float* __restrict__ b_subj,
    const float* __restrict__ w_obj, const float* __restrict__ b_obj,
    u16* __restrict__ muT, u16* __restrict__ w1t, u16* __restrict__ w2t,
    u16* __restrict__ wuT, u16* __restrict__ wvrT, u16* __restrict__ wm1T,
    float* __restrict__ px, int P){
  __shared__ float smem[4160];
  int bid = blockIdx.x, t = threadIdx.x;
  if (bid < 1600){
    int b = bid >> 4, icb = bid & 15;
    int s0, s1; segrange(im_idx, P, b, s0, s1);
    float inv = 1.f / fmaxf((float)(s1 - s0), 1.f);
    f4v a0 = {}, a1 = {}, a2 = {}, a3 = {};
    int p = s0;
    for (; p + 1 < s1; p += 2){
      const f4v* x = (const f4v*)(uf + (size_t)p*50176 + icb*3136);
      const f4v* y = (const f4v*)(uf + (size_t)(p+1)*50176 + icb*3136);
      a0 += x[t] + y[t]; a1 += x[t+256] + y[t+256]; a2 += x[t+512] + y[t+512];
      if (t < 16) a3 += x[t+768] + y[t+768];
    }
    if (p < s1){
      const f4v* x = (const f4v*)(uf + (size_t)p*50176 + icb*3136);
      a0 += x[t]; a1 += x[t+256]; a2 += x[t+512];
      if (t < 16) a3 += x[t+768];
    }
    *(f4v*)&smem[4*t] = a0;
    *(f4v*)&smem[4*(t+256)] = a1;
    *(f4v*)&smem[4*(t+512)] = a2;
    if (t < 16) *(f4v*)&smem[4*(t+768)] = a3;
    __syncthreads();
    for (int o = t; o < 3136; o += 256){
      int pix = o >> 6, ics = o & 63;
      muT[(size_t)(b*49 + pix)*1024 + (icb<<6) + ics] = f2b(smem[ics*49 + pix]*inv);
    }
  } else if (bid < 1800){
    int i = bid - 1600; int b = i >> 1, s = i & 1;
    int s0, s1; segrange(im_idx, P, b, s0, s1);
    float inv = 1.f / fmaxf((float)(s1 - s0), 1.f);
    f4v a0 = {}, a1 = {};
    for (int p = s0; p < s1; ++p){
      int row = pidx[p*2 + s];
      const f4v* src = (const f4v*)(feat + (size_t)row*2048);
      a0 += src[t]; a1 += src[t+256];
    }
    ((f4v*)smem)[t] = a0*inv; ((f4v*)smem)[t+256] = a1*inv;
    __syncthreads();
    const float* W  = s ? w_obj : w_subj;
    const float* bi = s ? b_obj : b_subj;
    float acc0 = bi[t], acc1 = bi[t+256];
    for (int k = 0; k < 2048; ++k){
      float pv = smem[k];
      acc0 += pv * W[(size_t)k*512 + t];
      acc1 += pv * W[(size_t)k*512 + t + 256];
    }
    px[b*1536 + s*512 + t] = acc0;
    px[b*1536 + s*512 + t + 256] = acc1;
  } else if (bid < 1864){
    int i = (bid - 1800)*256 + t;          // [128 oc][128 k]
    int k = i & 127;
    w1t[i] = f2b(k < 98 ? w_c1[(i>>7)*98 + k] : 0.f);
  } else if (bid < 3016){
    int i = (bid - 1864)*256 + t;          // [9 tap][256 oc][128 ic]
    int tap = i >> 15, r = i & 32767;
    w2t[i] = f2b(w_c2[((r>>7)*128 + (r & 127))*9 + tap]);
  } else if (bid < 4040){
    int i = (bid - 3016)*256 + t;
    wuT[i] = f2b(w_u[i]);
  } else if (bid < 5608){
    int idx = bid - 4040;                  // 196*8
    transpose_body(w_vr, wvrT, 12544, 512, idx >> 3, idx & 7, t, smem);
  } else {
    int idx = bid - 5608;                  // 24*32
    transpose_body(w_m1, wm1T, 1536, 2048, idx >> 5, idx & 31, t, smem);
  }
}

// ========== conv1 (7x7 s2 p3, 2->128) single fused pass: MFMA -> relu -> BN1 stats + maxpool(pre-BN) ==========
__global__ __launch_bounds__(256) void k_conv1(const float* __restrict__ masks, const u16* __restrict__ w1t,
                                               const float* __restrict__ b1,
                                               float* __restrict__ stats1, u16* __restrict__ spool){
  __shared__ float in_lds[2178];    // [2][33][33] zero-padded input
  __shared__ u16 a2col[28288];      // [208 m][136 k] bf16; reused as s1n[128][196]
  int p = blockIdx.x, t = threadIdx.x;
  int lane = t & 63, w = t >> 6;
  int l15 = lane & 15, lhi = lane >> 4;
  {
    f4v z = {}; f4v* a4 = (f4v*)a2col;
    for (int i = t; i < 3536; i += 256) a4[i] = z;
    for (int i = t; i < 2178; i += 256) in_lds[i] = 0.f;
  }
  __syncthreads();
  for (int e = t; e < 1458; e += 256){
    int c = e / 729, r = e - c*729;
    in_lds[c*1089 + (r/27 + 3)*33 + (r%27 + 3)] = masks[(size_t)p*1458 + e];
  }
  __syncthreads();
  for (int e = t; e < 19208; e += 256){                   // im2col: A[pix][k], k = ic*49+ky*7+kx
    int pix = e / 98, k = e - pix*98;
    int ic = k / 49, r = k - ic*49;
    int ky = r / 7, kx = r - ky*7;
    int oy = pix / 14, ox = pix - oy*14;
    a2col[pix*136 + k] = f2b(in_lds[ic*1089 + (oy*2 + ky)*33 + (ox*2 + kx)]);
  }
  __syncthreads();
  f4v acc[13][2] = {};
  int ocb = w*32;
  for (int kst = 0; kst < 4; ++kst){
    int koff = kst*32 + lhi*8;
    s8v B0 = *(const s8v*)&w1t[(ocb + l15)*128 + koff];
    s8v B1 = *(const s8v*)&w1t[(ocb + 16 + l15)*128 + koff];
    #pragma unroll
    for (int mt = 0; mt < 13; ++mt){
      s8v A = *(const s8v*)&a2col[(mt*16 + l15)*136 + koff];
      acc[mt][0] = mfma16(A, B0, acc[mt][0]);
      acc[mt][1] = mfma16(A, B1, acc[mt][1]);
    }
  }
  __syncthreads();                       // all waves done reading a2col before s1n overwrite
  u16* s1n = a2col;                      // [128 oc][196 pix] bf16, PRE-BN relu
  float ss[2] = {0,0}, qq[2] = {0,0};
  #pragma unroll
  for (int n = 0; n < 2; ++n){
    int oc = ocb + n*16 + l15;
    float bias = b1[oc];
    #pragma unroll
    for (int mt = 0; mt < 13; ++mt)
      #pragma unroll
      for (int v = 0; v < 4; ++v){
        int pix = mt*16 + lhi*4 + v;
        if (pix < 196){
          float r = fmaxf(acc[mt][n][v] + bias, 0.f);
          ss[n] += r; qq[n] += r*r;
          s1n[oc*196 + pix] = f2b(r);
        }
      }
  }
  #pragma unroll
  for (int n = 0; n < 2; ++n){
    float s = ss[n], q = qq[n];
    s += __shfl_xor(s, 16); s += __shfl_xor(s, 32);
    q += __shfl_xor(q, 16); q += __shfl_xor(q, 32);
    if (lane < 16){
      atomicAdd(&stats1[ocb + n*16 + lane], s);
      atomicAdd(&stats1[128 + ocb + n*16 + lane], q);
    }
  }
  __syncthreads();
  for (int j = t; j < 6272; j += 256){   // maxpool 3x3 s2 p1 on 14x14 -> 7x7 (pre-BN; BN is monotone)
    int oc = j & 127, pp = j >> 7;
    int poy = pp / 7, pox = pp - poy*7;
    float m = -3.4e38f;
    #pragma unroll
    for (int dy = 0; dy < 3; ++dy){
      int iy = poy*2 - 1 + dy;
      if (iy < 0 || iy > 13) continue;
      #pragma unroll
      for (int dx = 0; dx < 3; ++dx){
        int ix = pox*2 - 1 + dx;
        if (ix < 0 || ix > 13) continue;
        m = fmaxf(m, b2f(s1n[oc*196 + iy*14 + ix]));
      }
    }
    spool[((size_t)p*49 + pp)*128 + oc] = f2b(m);
  }
}

// ========== conv2 (3x3 s1 p1, 128->256): BN1 on staging, 2-pair M-tiles, relu -> segsum + BN2 stats ==========
__global__ __launch_bounds__(512) void k_conv2(const u16* __restrict__ spool, const u16* __restrict__ w2t,
                                               const float* __restrict__ b2,
                                               const float* __restrict__ g1, const float* __restrict__ be1,
                                               const float* __restrict__ stats1, const int* __restrict__ im_idx,
                                               float* __restrict__ segr, float* __restrict__ stats2,
                                               int P, float invN1){
  __shared__ u16 inT[164*136];     // rows: ppix*2+pair (0..161), 162 = zero row; stride 136 u16
  __shared__ float sc1[128], sh1[128];
  int b = blockIdx.x, q = blockIdx.y, t = threadIdx.x;
  int lane = t & 63, w = t >> 6;
  int l15 = lane & 15, lhi = lane >> 4;
  {
    f4v z = {}; f4v* a4 = (f4v*)inT;
    for (int i = t; i < 2788; i += 512) a4[i] = z;
  }
  if (t < 128){                    // folded bnfin1
    float mean = stats1[t]*invN1;
    float var  = stats1[128 + t]*invN1 - mean*mean;
    float sc = g1[t]*rsqrtf(var + 1e-5f);
    sc1[t] = sc; sh1[t] = be1[t] - mean*sc;
  }
  int s0, s1; segrange(im_idx, P, b, s0, s1);
  int cnt = s1 - s0, chunk = (cnt + 4)/5;
  int p0 = s0 + q*chunk, p1 = min(p0 + chunk, s1);
  int ocb = w*32;
  int pym[7], pxm[7], prm[7]; bool okm[7];
  #pragma unroll
  for (int mt = 0; mt < 7; ++mt){
    int row = mt*16 + l15;
    int pix = row >> 1; prm[mt] = row & 1;
    okm[mt] = pix < 49;
    pym[mt] = pix/7; pxm[mt] = pix - pym[mt]*7;
  }
  float bias[2];
  bias[0] = b2[ocb + l15]; bias[1] = b2[ocb + 16 + l15];
  f4v segacc[7][2] = {};
  float ssum[2] = {0,0}, ssq[2] = {0,0};
  for (int p = p0; p < p1; p += 2){
    __syncthreads();
    int hasB = (p + 1 < p1);
    for (int j = t; j < 6272; j += 512){
      int pp = j >= 3136;
      if (pp && !hasB) break;
      int i = j - pp*3136;
      u32 v = ((const u32*)(spool + (size_t)(p + pp)*6272))[i];
      int pix = i >> 6, icp = i & 63;
      float lo = b2f((u16)v)*sc1[icp*2]     + sh1[icp*2];
      float hi = b2f((u16)(v >> 16))*sc1[icp*2 + 1] + sh1[icp*2 + 1];
      int py = pix/7, pxx = pix - py*7;
      int row = ((py + 1)*9 + pxx + 1)*2 + pp;
      ((u32*)inT)[row*68 + icp] = (u32)f2b(lo) | ((u32)f2b(hi) << 16);
    }
    __syncthreads();
    f4v pacc[7][2] = {};
    #pragma unroll
    for (int tap = 0; tap < 9; ++tap){
      int dy = tap/3 - 1, dx = tap%3 - 1;
      int rowb[7];
      #pragma unroll
      for (int mt = 0; mt < 7; ++mt)
        rowb[mt] = okm[mt] ? (((pym[mt] + 1 + dy)*9 + pxm[mt] + 1 + dx)*2 + prm[mt])*136 : 162*136;
      for (int kst = 0; kst < 4; ++kst){
        int koff = kst*32 + lhi*8;
        s8v B0 = *(const s8v*)&w2t[(size_t)(tap*256 + ocb + l15)*128 + koff];
        s8v B1 = *(const s8v*)&w2t[(size_t)(tap*256 + ocb + 16 + l15)*128 + koff];
        #pragma unroll
        for (int mt = 0; mt < 7; ++mt){
          s8v A = *(const s8v*)&inT[rowb[mt] + koff];
          pacc[mt][0] = mfma16(A, B0, pacc[mt][0]);
          pacc[mt][1] = mfma16(A, B1, pacc[mt][1]);
        }
      }
    }
    #pragma unroll
    for (int n = 0; n < 2; ++n)
      #pragma unroll
      for (int mt = 0; mt < 7; ++mt)
        #pragma unroll
        for (int v = 0; v < 4; ++v){
          int row = mt*16 + lhi*4 + v;
          int pix = row >> 1, pr = row & 1;
          float r = fmaxf(pacc[mt][n][v] + bias[n], 0.f);
          r = (pix < 49 && (pr == 0 || hasB)) ? r : 0.f;
          segacc[mt][n][v] += r;
          ssum[n] += r; ssq[n] += r*r;
        }
  }
  #pragma unroll
  for (int n = 0; n < 2; ++n){
    int oc = ocb + n*16 + l15;
    #pragma unroll
    for (int mt = 0; mt < 7; ++mt){
      int pix0 = (mt*16 + lhi*4) >> 1;
      if (pix0 < 49)
        atomicAdd(&segr[(size_t)(b*256 + oc)*49 + pix0], segacc[mt][n][0] + segacc[mt][n][1]);
      if (pix0 + 1 < 49)
        atomicAdd(&segr[(size_t)(b*256 + oc)*49 + pix0 + 1], segacc[mt][n][2] + segacc[mt][n][3]);
    }
    float s = ssum[n], qd = ssq[n];
    s  += __shfl_xor(s, 16);  s  += __shfl_xor(s, 32);
    qd += __shfl_xor(qd, 16); qd += __shfl_xor(qd, 32);
    if (lane < 16){
      atomicAdd(&stats2[ocb + n*16 + lane], s);
      atomicAdd(&stats2[256 + ocb + n*16 + lane], qd);
    }
  }
}

// ========== combine: union 1x1 conv (pooled) + bn2(seg-mean relu2), folded bnfin2 -> tbf ==========
__global__ __launch_bounds__(256) void k_combine(const u16* __restrict__ muT, const u16* __restrict__ wuT,
                                                 const float* __restrict__ b_u, const float* __restrict__ segr,
                                                 const float* __restrict__ stats2,
                                                 const float* __restrict__ g2, const float* __restrict__ be2,
                                                 const int* __restrict__ im_idx, u16* __restrict__ tbf,
                                                 int P, float invN2){
  __shared__ float sc2[256], sh2[256];
  int b = blockIdx.x, t = threadIdx.x;
  int lane = t & 63, w = t >> 6;
  int l15 = lane & 15, lhi = lane >> 4;
  {
    float mean = stats2[t]*invN2;
    float var  = stats2[256 + t]*invN2 - mean*mean;
    float sc = g2[t]*rsqrtf(var + 1e-5f);
    sc2[t] = sc; sh2[t] = be2[t] - mean*sc;
  }
  __syncthreads();
  int s0, s1; segrange(im_idx, P, b, s0, s1);
  float inv = 1.f / fmaxf((float)(s1 - s0), 1.f);
  int ocb = w*64;
  const u16* arow[4];
  #pragma unroll
  for (int mt = 0; mt < 4; ++mt){
    int pix = mt*16 + l15;
    arow[mt] = muT + (size_t)(b*49 + (pix < 49 ? pix : 0))*1024;   // invalid rows discarded at store
  }
  f4v acc[4][4] = {};
  for (int kst = 0; kst < 32; ++kst){
    int koff = kst*32 + lhi*8;
    s8v Bf[4];
    #pragma unroll
    for (int nt = 0; nt < 4; ++nt)
      Bf[nt] = *(const s8v*)&wuT[(ocb + nt*16 + l15)*1024 + koff];
    #pragma unroll
    for (int mt = 0; mt < 4; ++mt){
      s8v A = *(const s8v*)&arow[mt][koff];
      #pragma unroll
      for (int nt = 0; nt < 4; ++nt)
        acc[mt][nt] = mfma16(A, Bf[nt], acc[mt][nt]);
    }
  }
  #pragma unroll
  for (int nt = 0; nt < 4; ++nt){
    int oc = ocb + nt*16 + l15;
    float bu = b_u[oc], sc = sc2[oc], sh = sh2[oc];
    #pragma unroll
    for (int mt = 0; mt < 4; ++mt)
      #pragma unroll
      for (int v = 0; v < 4; ++v){
        int pix = mt*16 + lhi*4 + v;
        if (pix < 49){
          float val = acc[mt][nt][v] + bu + sc*segr[(size_t)(b*256 + oc)*49 + pix]*inv + sh;
          tbf[(size_t)b*12544 + oc*49 + pix] = f2b(val);
        }
      }
  }
}

// ========== vr GEMM: [112,12544]@[12544,512], k-split, b_vr bias at kc==0, atomic into px cols 1024.. ==========
__global__ __launch_bounds__(256) void k_vr(const u16* __restrict__ tbf, const u16* __restrict__ wvrT,
                                            const float* __restrict__ b_vr, float* __restrict__ px, int B){
  int nb = blockIdx.x, kc = blockIdx.y, t = threadIdx.x;
  int lane = t & 63, w = t >> 6;
  int l15 = lane & 15, lhi = lane >> 4;
  int colb = nb*256 + w*64;
  int k0 = kc*448;
  f4v acc[7][4] = {};
  for (int kst = 0; kst < 14; ++kst){
    int koff = k0 + kst*32 + lhi*8;
    s8v Bf[4];
    #pragma unroll
    for (int nt = 0; nt < 4; ++nt)
      Bf[nt] = *(const s8v*)&wvrT[(size_t)(colb + nt*16 + l15)*12544 + koff];
    #pragma unroll
    for (int mt = 0; mt < 7; ++mt){
      s8v A = *(const s8v*)&tbf[(size_t)(mt*16 + l15)*12544 + koff];
      #pragma unroll
      for (int nt = 0; nt < 4; ++nt)
        acc[mt][nt] = mfma16(A, Bf[nt], acc[mt][nt]);
    }
  }
  #pragma unroll
  for (int nt = 0; nt < 4; ++nt){
    int col = colb + nt*16 + l15;
    float bias = (kc == 0) ? b_vr[col] : 0.f;
    #pragma unroll
    for (int mt = 0; mt < 7; ++mt)
      #pragma unroll
      for (int v = 0; v < 4; ++v){
        int row = mt*16 + lhi*4 + v;
        if (row < B) atomicAdd(&px[row*1536 + 1024 + col], acc[mt][nt][v] + bias);
      }
  }
}

// ========== MLP m1: [112,1536]@[1536,2048], k-split atomics; A = f32 px converted inline ==========
__global__ __launch_bounds__(256) void k_m1(const float* __restrict__ px, const u16* __restrict__ wm1T,
                                            float* __restrict__ h, int B){
  int nb = blockIdx.x, kc = blockIdx.y, t = threadIdx.x;
  int lane = t & 63, w = t >> 6;
  int l15 = lane & 15, lhi = lane >> 4;
  int colb = nb*256 + w*64;
  int k0 = kc*384;
  f4v acc[7][4] = {};
  for (int kst = 0; kst < 12; ++kst){
    int koff = k0 + kst*32 + lhi*8;
    s8v Bf[4];
    #pragma unroll
    for (int nt = 0; nt < 4; ++nt)
      Bf[nt] = *(const s8v*)&wm1T[(size_t)(colb + nt*16 + l15)*1536 + koff];
    #pragma unroll
    for (int mt = 0; mt < 7; ++mt){
      const float* ap = px + (size_t)(mt*16 + l15)*1536 + koff;
      f4v lo = *(const f4v*)ap;
      f4v hi = *(const f4v*)(ap + 4);
      s8v A;
      A[0] = (short)f2b(lo[0]); A[1] = (short)f2b(lo[1]);
      A[2] = (short)f2b(lo[2]); A[3] = (short)f2b(lo[3]);
      A[4] = (short)f2b(hi[0]); A[5] = (short)f2b(hi[1]);
      A[6] = (short)f2b(hi[2]); A[7] = (short)f2b(hi[3]);
      #pragma unroll
      for (int nt = 0; nt < 4; ++nt)
        acc[mt][nt] = mfma16(A, Bf[nt], acc[mt][nt]);
    }
  }
  #pragma unroll
  for (int nt = 0; nt < 4; ++nt){
    int col = colb + nt*16 + l15;
    #pragma unroll
    for (int mt = 0; mt < 7; ++mt)
      #pragma unroll
      for (int v = 0; v < 4; ++v){
        int row = mt*16 + lhi*4 + v;
        if (row < B) atomicAdd(&h[row*2048 + col], acc[mt][nt][v]);
      }
  }
}

// ========== m2 + bias1/relu on the fly + sigmoid ==========
__global__ __launch_bounds__(192) void k_m2(const float* __restrict__ h, const float* __restrict__ bm1,
                                            const float* __restrict__ w_m2, const float* __restrict__ b_m2,
                                            float* __restrict__ out){
  int b = blockIdx.x, col = threadIdx.x;
  if (col >= 157) return;
  float acc = b_m2[col];
  const float* hb = h + (size_t)b*2048;
  for (int k = 0; k < 2048; ++k)
    acc += fmaxf(hb[k] + bm1[k], 0.f) * w_m2[(size_t)k*157 + col];
  out[b*157 + col] = 1.f/(1.f + expf(-acc));
}

extern "C" void kernel_launch(void* const* d_in, const int* in_sizes, int n_in,
                              void* d_out, int out_size, void* d_ws, size_t ws_size,
                              hipStream_t stream){
  const float* features   = (const float*)d_in[0];
  const float* union_feat = (const float*)d_in[1];
  const float* masks      = (const float*)d_in[2];
  const float* w_union    = (const float*)d_in[3];
  const float* b_union    = (const float*)d_in[4];
  const float* w_c1       = (const float*)d_in[5];
  const float* b_c1       = (const float*)d_in[6];
  const float* g_bn1      = (const float*)d_in[7];
  const float* be_bn1     = (const float*)d_in[8];
  const float* w_c2       = (const float*)d_in[9];
  const float* b_c2       = (const float*)d_in[10];
  const float* g_bn2      = (const float*)d_in[11];
  const float* be_bn2     = (const float*)d_in[12];
  const float* w_subj     = (const float*)d_in[13];
  const float* b_subj     = (const float*)d_in[14];
  const float* w_obj      = (const float*)d_in[15];
  const float* b_obj      = (const float*)d_in[16];
  const float* w_vr       = (const float*)d_in[17];
  const float* b_vr       = (const float*)d_in[18];
  const float* w_m1       = (const float*)d_in[19];
  const float* b_m1       = (const float*)d_in[20];
  const float* w_m2       = (const float*)d_in[21];
  const float* b_m2       = (const float*)d_in[22];
  const int* pair_idx     = (const int*)d_in[23];
  const int* im_idx       = (const int*)d_in[24];
  float* out = (float*)d_out;
  const int P = in_sizes[24];
  const int B = out_size/157;

  char* ws = (char*)d_ws;
  size_t off = 0;
  auto alloc = [&](size_t bytes)->size_t{ size_t o = off; off += (bytes + 255) & ~(size_t)255; return o; };
  size_t o_muT  = alloc((size_t)B*49*1024*2);
  size_t o_spool= alloc((size_t)P*49*128*2);
  size_t o_w1t  = alloc(128*128*2);
  size_t o_w2t  = alloc(9*256*128*2);
  size_t o_wuT  = alloc(256*1024*2);
  size_t o_wvrT = alloc((size_t)512*12544*2);
  size_t o_wm1T = alloc((size_t)2048*1536*2);
  size_t o_stats= alloc(3072);
  size_t o_segr = alloc((size_t)B*256*49*4);
  size_t o_tbf  = alloc((size_t)112*12544*2);
  size_t o_px   = alloc((size_t)112*1536*4);
  size_t o_h    = alloc((size_t)B*2048*4);
  (void)ws_size; (void)n_in;

  float* stats1 = (float*)(ws + o_stats);
  float* stats2 = stats1 + 256;
  u16*   muT    = (u16*)(ws + o_muT);
  u16*   spool  = (u16*)(ws + o_spool);
  u16*   w1t    = (u16*)(ws + o_w1t);
  u16*   w2t    = (u16*)(ws + o_w2t);
  u16*   wuT    = (u16*)(ws + o_wuT);
  u16*   wvrT   = (u16*)(ws + o_wvrT);
  u16*   wm1T   = (u16*)(ws + o_wm1T);
  float* segr   = (float*)(ws + o_segr);
  u16*   tbf    = (u16*)(ws + o_tbf);
  float* px     = (float*)(ws + o_px);
  float* h      = (float*)(ws + o_h);

  hipMemsetAsync(ws + o_stats, 0, 3072, stream);
  hipMemsetAsync(ws + o_segr, 0, (size_t)B*256*49*4, stream);
  hipMemsetAsync(ws + o_px, 0, (size_t)112*1536*4, stream);
  hipMemsetAsync(ws + o_h, 0, (size_t)B*2048*4, stream);

  dim3 blk(256);
  k_pre<<<6376, blk, 0, stream>>>(union_feat, features, pair_idx, im_idx,
                                  w_c1, w_c2, w_union, w_vr, w_m1,
                                  w_subj, b_subj, w_obj, b_obj,
                                  muT, w1t, w2t, wuT, wvrT, wm1T, px, P);
  k_conv1<<<P, blk, 0, stream>>>(masks, w1t, b_c1, stats1, spool);
  k_conv2<<<dim3(B, 5), dim3(512), 0, stream>>>(spool, w2t, b_c2, g_bn1, be_bn1, stats1, im_idx,
                                                segr, stats2, P, 1.f/((float)P*196.f));
  k_combine<<<B, blk, 0, stream>>>(muT, wuT, b_union, segr, stats2, g_bn2, be_bn2, im_idx,
                                   tbf, P, 1.f/((float)P*49.f));
  k_vr<<<dim3(2, 28), blk, 0, stream>>>(tbf, wvrT, b_vr, px, B);
  k_m1<<<dim3(8, 4), blk, 0, stream>>>(px, wm1T, h, B);
  k_m2<<<B, dim3(192), 0, stream>>>(h, b_m1, w_m2, b_m2, out);
}

// Round 3
// 1433.093 us; speedup vs baseline: 1.1445x; 1.0106x over previous
//
#include <hip/hip_runtime.h>

typedef unsigned short u16;
typedef unsigned int   u32;
typedef short s8v __attribute__((ext_vector_type(8)));   // 8 x bf16 (4 VGPR) MFMA operand
typedef float f4v __attribute__((ext_vector_type(4)));   // MFMA accumulator

#define DEV __device__ __forceinline__

DEV u16 f2b(float f){                      // f32 -> bf16, round-to-nearest-even
  u32 x = __builtin_bit_cast(u32, f);
  u32 r = x + 0x7fffu + ((x >> 16) & 1u);
  return (u16)(r >> 16);
}
DEV float b2f(u16 u){ u32 x = ((u32)u) << 16; return __builtin_bit_cast(float, x); }
DEV f4v mfma16(s8v a, s8v b, f4v c){ return __builtin_amdgcn_mfma_f32_16x16x32_bf16(a, b, c, 0, 0, 0); }

// binary-search segment [s0,s1) of image b in sorted im_idx
DEV void segrange(const int* __restrict__ im, int P, int b, int& s0, int& s1){
  int lo = 0, hi = P;
  while (lo < hi){ int m = (lo + hi) >> 1; if (im[m] < b) lo = m + 1; else hi = m; }
  s0 = lo;
  int lo2 = lo; hi = P;
  while (lo2 < hi){ int m = (lo2 + hi) >> 1; if (im[m] < b + 1) lo2 = m + 1; else hi = m; }
  s1 = lo2;
}

DEV void transpose_body(const float* __restrict__ src, u16* __restrict__ dst,
                        int R, int C, int rb, int cb, int t, float* tile){
  int r0 = rb << 6, c0 = cb << 6;
  for (int i = t; i < 4096; i += 256){
    int rl = i >> 6, cl = i & 63;
    tile[rl*65 + cl] = src[(size_t)(r0 + rl)*C + c0 + cl];
  }
  __syncthreads();
  for (int i = t; i < 4096; i += 256){
    int cl = i >> 6, rl = i & 63;
    dst[(size_t)(c0 + cl)*R + r0 + rl] = f2b(tile[rl*65 + cl]);
  }
}

// ================= k_pre: ALL input-only work fused (overlaps under union_pool's HBM floor) ========
__global__ __launch_bounds__(256) void k_pre(
    const float* __restrict__ uf, const float* __restrict__ feat,
    const int* __restrict__ pidx, const int* __restrict__ im_idx,
    const float* __restrict__ w_c1, const float* __restrict__ w_c2, const float* __restrict__ w_u,
    const float* __restrict__ w_vr, const float* __restrict__ w_m1,
    const float* __restrict__ w_subj, const float* __restrict__ b_subj,
    const float* __restrict__ w_obj, const float* __restrict__ b_obj,
    u16* __restrict__ muT, u16* __restrict__ w1t, u16* __restrict__ w2t,
    u16* __restrict__ wuT, u16* __restrict__ wvrT, u16* __restrict__ wm1T,
    float* __restrict__ px, int P){
  __shared__ float smem[4160];
  int bid = blockIdx.x, t = threadIdx.x;
  if (bid < 1600){
    int b = bid >> 4, icb = bid & 15;
    int s0, s1; segrange(im_idx, P, b, s0, s1);
    float inv = 1.f / fmaxf((float)(s1 - s0), 1.f);
    f4v a0 = {}, a1 = {}, a2 = {}, a3 = {};
    int p = s0;
    for (; p + 1 < s1; p += 2){
      const f4v* x = (const f4v*)(uf + (size_t)p*50176 + icb*3136);
      const f4v* y = (const f4v*)(uf + (size_t)(p+1)*50176 + icb*3136);
      a0 += x[t] + y[t]; a1 += x[t+256] + y[t+256]; a2 += x[t+512] + y[t+512];
      if (t < 16) a3 += x[t+768] + y[t+768];
    }
    if (p < s1){
      const f4v* x = (const f4v*)(uf + (size_t)p*50176 + icb*3136);
      a0 += x[t]; a1 += x[t+256]; a2 += x[t+512];
      if (t < 16) a3 += x[t+768];
    }
    *(f4v*)&smem[4*t] = a0;
    *(f4v*)&smem[4*(t+256)] = a1;
    *(f4v*)&smem[4*(t+512)] = a2;
    if (t < 16) *(f4v*)&smem[4*(t+768)] = a3;
    __syncthreads();
    for (int o = t; o < 3136; o += 256){
      int pix = o >> 6, ics = o & 63;
      muT[(size_t)(b*49 + pix)*1024 + (icb<<6) + ics] = f2b(smem[ics*49 + pix]*inv);
    }
  } else if (bid < 1800){
    int i = bid - 1600; int b = i >> 1, s = i & 1;
    int s0, s1; segrange(im_idx, P, b, s0, s1);
    float inv = 1.f / fmaxf((float)(s1 - s0), 1.f);
    f4v a0 = {}, a1 = {};
    for (int p = s0; p < s1; ++p){
      int row = pidx[p*2 + s];
      const f4v* src = (const f4v*)(feat + (size_t)row*2048);
      a0 += src[t]; a1 += src[t+256];
    }
    ((f4v*)smem)[t] = a0*inv; ((f4v*)smem)[t+256] = a1*inv;
    __syncthreads();
    const float* W  = s ? w_obj : w_subj;
    const float* bi = s ? b_obj : b_subj;
    float acc0 = bi[t], acc1 = bi[t+256];
    for (int k = 0; k < 2048; ++k){
      float pv = smem[k];
      acc0 += pv * W[(size_t)k*512 + t];
      acc1 += pv * W[(size_t)k*512 + t + 256];
    }
    px[b*1536 + s*512 + t] = acc0;
    px[b*1536 + s*512 + t + 256] = acc1;
  } else if (bid < 1864){
    int i = (bid - 1800)*256 + t;          // [128 oc][128 k]
    int k = i & 127;
    w1t[i] = f2b(k < 98 ? w_c1[(i>>7)*98 + k] : 0.f);
  } else if (bid < 3016){
    int i = (bid - 1864)*256 + t;          // [9 tap][256 oc][128 ic]
    int tap = i >> 15, r = i & 32767;
    w2t[i] = f2b(w_c2[((r>>7)*128 + (r & 127))*9 + tap]);
  } else if (bid < 4040){
    int i = (bid - 3016)*256 + t;
    wuT[i] = f2b(w_u[i]);
  } else if (bid < 5608){
    int idx = bid - 4040;                  // 196*8
    transpose_body(w_vr, wvrT, 12544, 512, idx >> 3, idx & 7, t, smem);
  } else {
    int idx = bid - 5608;                  // 24*32
    transpose_body(w_m1, wm1T, 1536, 2048, idx >> 5, idx & 31, t, smem);
  }
}

// ========== conv1 (7x7 s2 p3, 2->128): hoisted-k im2col, reg-resident B, fused stats + u16 maxpool ==========
__global__ __launch_bounds__(256) void k_conv1(const float* __restrict__ masks, const u16* __restrict__ w1t,
                                               const float* __restrict__ b1,
                                               float* __restrict__ stats1, u16* __restrict__ spool){
  __shared__ u16 in_bf[2178];       // [2][33][33] zero-padded input, bf16
  __shared__ u16 a2col[28288];      // [208 m][136 k]; reused as s1n[128 oc][196 pix]
  int p = blockIdx.x, t = threadIdx.x;
  int lane = t & 63, w = t >> 6;
  int l15 = lane & 15, lhi = lane >> 4;
  s8v Bf[4][2];                     // whole B panel in regs (w1t is 32KB, L2-hot)
  #pragma unroll
  for (int kst = 0; kst < 4; ++kst){
    Bf[kst][0] = *(const s8v*)&w1t[(w*32 + l15)*128 + kst*32 + lhi*8];
    Bf[kst][1] = *(const s8v*)&w1t[(w*32 + 16 + l15)*128 + kst*32 + lhi*8];
  }
  for (int i = t; i < 1089; i += 256) ((u32*)in_bf)[i] = 0;
  for (int i = t; i < 768; i += 256){            // zero only pad rows 196..207, k<128
    int r = i >> 6, c = i & 63;
    ((u32*)&a2col[(196 + r)*136])[c] = 0;
  }
  __syncthreads();
  for (int e = t; e < 1458; e += 256){
    int c = e >= 729; int r = e - c*729;
    int rr = r/27, cc = r - rr*27;
    in_bf[c*1089 + (rr + 3)*33 + cc + 3] = f2b(masks[(size_t)p*1458 + e]);
  }
  __syncthreads();
  {                                  // im2col with per-thread-constant k
    int k = t & 127;
    bool valid = k < 98;
    int ic = k >= 49; int r = k - ic*49;
    int ky = r/7, kx = r - ky*7;
    int sbase = ic*1089 + ky*33 + kx;
    for (int pix = t >> 7; pix < 196; pix += 2){
      int oy = pix/14, ox = pix - oy*14;
      a2col[pix*136 + k] = valid ? in_bf[sbase + oy*66 + ox*2] : (u16)0;
    }
  }
  __syncthreads();
  f4v acc[13][2] = {};
  #pragma unroll
  for (int kst = 0; kst < 4; ++kst){
    int koff = kst*32 + lhi*8;
    #pragma unroll
    for (int mt = 0; mt < 13; ++mt){
      s8v A = *(const s8v*)&a2col[(mt*16 + l15)*136 + koff];
      acc[mt][0] = mfma16(A, Bf[kst][0], acc[mt][0]);
      acc[mt][1] = mfma16(A, Bf[kst][1], acc[mt][1]);
    }
  }
  __syncthreads();                       // all waves done reading a2col before s1n overwrite
  u16* s1n = a2col;                      // [128 oc][196 pix], PRE-BN relu (BN applied in conv2; maxpool∘BN commutes)
  int ocb = w*32;
  float ss[2] = {0,0}, qq[2] = {0,0};
  #pragma unroll
  for (int n = 0; n < 2; ++n){
    int oc = ocb + n*16 + l15;
    float bias = b1[oc];
    #pragma unroll
    for (int mt = 0; mt < 13; ++mt)
      #pragma unroll
      for (int v = 0; v < 4; ++v){
        int pix = mt*16 + lhi*4 + v;
        if (pix < 196){
          float r = fmaxf(acc[mt][n][v] + bias, 0.f);
          ss[n] += r; qq[n] += r*r;
          s1n[oc*196 + pix] = f2b(r);
        }
      }
  }
  #pragma unroll
  for (int n = 0; n < 2; ++n){
    float s = ss[n], q = qq[n];
    s += __shfl_xor(s, 16); s += __shfl_xor(s, 32);
    q += __shfl_xor(q, 16); q += __shfl_xor(q, 32);
    if (lane < 16){
      atomicAdd(&stats1[ocb + n*16 + lane], s);
      atomicAdd(&stats1[128 + ocb + n*16 + lane], q);
    }
  }
  __syncthreads();
  for (int j = t; j < 6272; j += 256){   // maxpool 3x3 s2 p1, u16-compare (relu => bits monotone)
    int oc = j & 127, pp = j >> 7;
    int poy = pp/7, pox = pp - poy*7;
    u32 m = 0;
    #pragma unroll
    for (int dy = 0; dy < 3; ++dy){
      int iy = poy*2 - 1 + dy;
      if (iy < 0 || iy > 13) continue;
      #pragma unroll
      for (int dx = 0; dx < 3; ++dx){
        int ix = pox*2 - 1 + dx;
        if (ix < 0 || ix > 13) continue;
        u32 v = s1n[oc*196 + iy*14 + ix];
        m = v > m ? v : m;
      }
    }
    spool[((size_t)p*49 + pp)*128 + oc] = (u16)m;
  }
}

// ========== conv2 (3x3 s1 p1, 128->256): BN1 on staging, per-tap B-batch, relu -> segsum + BN2 stats ==========
__global__ __launch_bounds__(512) void k_conv2(const u16* __restrict__ spool, const u16* __restrict__ w2t,
                                               const float* __restrict__ b2,
                                               const float* __restrict__ g1, const float* __restrict__ be1,
                                               const float* __restrict__ stats1, const int* __restrict__ im_idx,
                                               float* __restrict__ segr, float* __restrict__ stats2,
                                               int P, float invN1){
  __shared__ u16 inT[164*136];     // rows: ppix*2+pair (0..161), 162 = zero row; stride 136 u16
  __shared__ float sc1[128], sh1[128];
  int b = blockIdx.x, q = blockIdx.y, t = threadIdx.x;
  int lane = t & 63, w = t >> 6;
  int l15 = lane & 15, lhi = lane >> 4;
  {
    f4v z = {}; f4v* a4 = (f4v*)inT;
    for (int i = t; i < 2788; i += 512) a4[i] = z;
  }
  if (t < 128){                    // folded bnfin1
    float mean = stats1[t]*invN1;
    float var  = stats1[128 + t]*invN1 - mean*mean;
    float sc = g1[t]*rsqrtf(var + 1e-5f);
    sc1[t] = sc; sh1[t] = be1[t] - mean*sc;
  }
  int s0, s1; segrange(im_idx, P, b, s0, s1);
  int cnt = s1 - s0, chunk = (cnt + 4)/5;
  int p0 = s0 + q*chunk, p1 = min(p0 + chunk, s1);
  int ocb = w*32;
  int pym[7], pxm[7], prm[7]; bool okm[7];
  #pragma unroll
  for (int mt = 0; mt < 7; ++mt){
    int row = mt*16 + l15;
    int pix = row >> 1; prm[mt] = row & 1;
    okm[mt] = pix < 49;
    pym[mt] = pix/7; pxm[mt] = pix - pym[mt]*7;
  }
  float bias[2];
  bias[0] = b2[ocb + l15]; bias[1] = b2[ocb + 16 + l15];
  f4v segacc[7][2] = {};
  float ssum[2] = {0,0}, ssq[2] = {0,0};
  for (int p = p0; p < p1; p += 2){
    __syncthreads();
    int hasB = (p + 1 < p1);
    for (int j = t; j < 6272; j += 512){
      int pp = j >= 3136;
      if (pp && !hasB) break;
      int i = j - pp*3136;
      u32 v = ((const u32*)(spool + (size_t)(p + pp)*6272))[i];
      int pix = i >> 6, icp = i & 63;
      float lo = b2f((u16)v)*sc1[icp*2]     + sh1[icp*2];
      float hi = b2f((u16)(v >> 16))*sc1[icp*2 + 1] + sh1[icp*2 + 1];
      int py = pix/7, pxx = pix - py*7;
      int row = ((py + 1)*9 + pxx + 1)*2 + pp;
      ((u32*)inT)[row*68 + icp] = (u32)f2b(lo) | ((u32)f2b(hi) << 16);
    }
    __syncthreads();
    f4v pacc[7][2] = {};
    #pragma unroll
    for (int tap = 0; tap < 9; ++tap){
      int dy = tap/3 - 1, dx = tap%3 - 1;
      int rowb[7];
      #pragma unroll
      for (int mt = 0; mt < 7; ++mt)
        rowb[mt] = okm[mt] ? (((pym[mt] + 1 + dy)*9 + pxm[mt] + 1 + dx)*2 + prm[mt])*136 : 162*136;
      s8v Bt[4][2];                      // batch all 8 B-frag loads -> one L2 latency per tap
      #pragma unroll
      for (int kst = 0; kst < 4; ++kst){
        int koff = kst*32 + lhi*8;
        Bt[kst][0] = *(const s8v*)&w2t[(size_t)(tap*256 + ocb + l15)*128 + koff];
        Bt[kst][1] = *(const s8v*)&w2t[(size_t)(tap*256 + ocb + 16 + l15)*128 + koff];
      }
      #pragma unroll
      for (int kst = 0; kst < 4; ++kst){
        int koff = kst*32 + lhi*8;
        #pragma unroll
        for (int mt = 0; mt < 7; ++mt){
          s8v A = *(const s8v*)&inT[rowb[mt] + koff];
          pacc[mt][0] = mfma16(A, Bt[kst][0], pacc[mt][0]);
          pacc[mt][1] = mfma16(A, Bt[kst][1], pacc[mt][1]);
        }
      }
    }
    #pragma unroll
    for (int n = 0; n < 2; ++n)
      #pragma unroll
      for (int mt = 0; mt < 7; ++mt)
        #pragma unroll
        for (int v = 0; v < 4; ++v){
          int row = mt*16 + lhi*4 + v;
          int pix = row >> 1, pr = row & 1;
          float r = fmaxf(pacc[mt][n][v] + bias[n], 0.f);
          r = (pix < 49 && (pr == 0 || hasB)) ? r : 0.f;
          segacc[mt][n][v] += r;
          ssum[n] += r; ssq[n] += r*r;
        }
  }
  #pragma unroll
  for (int n = 0; n < 2; ++n){
    int oc = ocb + n*16 + l15;
    #pragma unroll
    for (int mt = 0; mt < 7; ++mt){
      int pix0 = (mt*16 + lhi*4) >> 1;
      if (pix0 < 49)
        atomicAdd(&segr[(size_t)(b*256 + oc)*49 + pix0], segacc[mt][n][0] + segacc[mt][n][1]);
      if (pix0 + 1 < 49)
        atomicAdd(&segr[(size_t)(b*256 + oc)*49 + pix0 + 1], segacc[mt][n][2] + segacc[mt][n][3]);
    }
    float s = ssum[n], qd = ssq[n];
    s  += __shfl_xor(s, 16);  s  += __shfl_xor(s, 32);
    qd += __shfl_xor(qd, 16); qd += __shfl_xor(qd, 32);
    if (lane < 16){
      atomicAdd(&stats2[ocb + n*16 + lane], s);
      atomicAdd(&stats2[256 + ocb + n*16 + lane], qd);
    }
  }
}

// ========== combine: union 1x1 conv (pooled) + bn2(seg-mean relu2), folded bnfin2 -> tbf ==========
__global__ __launch_bounds__(256) void k_combine(const u16* __restrict__ muT, const u16* __restrict__ wuT,
                                                 const float* __restrict__ b_u, const float* __restrict__ segr,
                                                 const float* __restrict__ stats2,
                                                 const float* __restrict__ g2, const float* __restrict__ be2,
                                                 const int* __restrict__ im_idx, u16* __restrict__ tbf,
                                                 int P, float invN2){
  __shared__ float sc2[256], sh2[256];
  int b = blockIdx.x, t = threadIdx.x;
  int lane = t & 63, w = t >> 6;
  int l15 = lane & 15, lhi = lane >> 4;
  {
    float mean = stats2[t]*invN2;
    float var  = stats2[256 + t]*invN2 - mean*mean;
    float sc = g2[t]*rsqrtf(var + 1e-5f);
    sc2[t] = sc; sh2[t] = be2[t] - mean*sc;
  }
  __syncthreads();
  int s0, s1; segrange(im_idx, P, b, s0, s1);
  float inv = 1.f / fmaxf((float)(s1 - s0), 1.f);
  int ocb = w*64;
  const u16* arow[4];
  #pragma unroll
  for (int mt = 0; mt < 4; ++mt){
    int pix = mt*16 + l15;
    arow[mt] = muT + (size_t)(b*49 + (pix < 49 ? pix : 0))*1024;   // invalid rows discarded at store
  }
  f4v acc[4][4] = {};
  for (int kst = 0; kst < 32; ++kst){
    int koff = kst*32 + lhi*8;
    s8v Bf[4];
    #pragma unroll
    for (int nt = 0; nt < 4; ++nt)
      Bf[nt] = *(const s8v*)&wuT[(ocb + nt*16 + l15)*1024 + koff];
    #pragma unroll
    for (int mt = 0; mt < 4; ++mt){
      s8v A = *(const s8v*)&arow[mt][koff];
      #pragma unroll
      for (int nt = 0; nt < 4; ++nt)
        acc[mt][nt] = mfma16(A, Bf[nt], acc[mt][nt]);
    }
  }
  #pragma unroll
  for (int nt = 0; nt < 4; ++nt){
    int oc = ocb + nt*16 + l15;
    float bu = b_u[oc], sc = sc2[oc], sh = sh2[oc];
    #pragma unroll
    for (int mt = 0; mt < 4; ++mt)
      #pragma unroll
      for (int v = 0; v < 4; ++v){
        int pix = mt*16 + lhi*4 + v;
        if (pix < 49){
          float val = acc[mt][nt][v] + bu + sc*segr[(size_t)(b*256 + oc)*49 + pix]*inv + sh;
          tbf[(size_t)b*12544 + oc*49 + pix] = f2b(val);
        }
      }
  }
}

// ========== vr GEMM: [112,12544]@[12544,512], k-split, b_vr bias at kc==0, atomic into px cols 1024.. ==========
__global__ __launch_bounds__(256) void k_vr(const u16* __restrict__ tbf, const u16* __restrict__ wvrT,
                                            const float* __restrict__ b_vr, float* __restrict__ px, int B){
  int nb = blockIdx.x, kc = blockIdx.y, t = threadIdx.x;
  int lane = t & 63, w = t >> 6;
  int l15 = lane & 15, lhi = lane >> 4;
  int colb = nb*256 + w*64;
  int k0 = kc*448;
  f4v acc[7][4] = {};
  for (int kst = 0; kst < 14; ++kst){
    int koff = k0 + kst*32 + lhi*8;
    s8v Bf[4];
    #pragma unroll
    for (int nt = 0; nt < 4; ++nt)
      Bf[nt] = *(const s8v*)&wvrT[(size_t)(colb + nt*16 + l15)*12544 + koff];
    #pragma unroll
    for (int mt = 0; mt < 7; ++mt){
      s8v A = *(const s8v*)&tbf[(size_t)(mt*16 + l15)*12544 + koff];
      #pragma unroll
      for (int nt = 0; nt < 4; ++nt)
        acc[mt][nt] = mfma16(A, Bf[nt], acc[mt][nt]);
    }
  }
  #pragma unroll
  for (int nt = 0; nt < 4; ++nt){
    int col = colb + nt*16 + l15;
    float bias = (kc == 0) ? b_vr[col] : 0.f;
    #pragma unroll
    for (int mt = 0; mt < 7; ++mt)
      #pragma unroll
      for (int v = 0; v < 4; ++v){
        int row = mt*16 + lhi*4 + v;
        if (row < B) atomicAdd(&px[row*1536 + 1024 + col], acc[mt][nt][v] + bias);
      }
  }
}

// ========== MLP m1: [112,1536]@[1536,2048], k-split atomics; A = f32 px converted inline ==========
__global__ __launch_bounds__(256) void k_m1(const float* __restrict__ px, const u16* __restrict__ wm1T,
                                            float* __restrict__ h, int B){
  int nb = blockIdx.x, kc = blockIdx.y, t = threadIdx.x;
  int lane = t & 63, w = t >> 6;
  int l15 = lane & 15, lhi = lane >> 4;
  int colb = nb*256 + w*64;
  int k0 = kc*384;
  f4v acc[7][4] = {};
  for (int kst = 0; kst < 12; ++kst){
    int koff = k0 + kst*32 + lhi*8;
    s8v Bf[4];
    #pragma unroll
    for (int nt = 0; nt < 4; ++nt)
      Bf[nt] = *(const s8v*)&wm1T[(size_t)(colb + nt*16 + l15)*1536 + koff];
    #pragma unroll
    for (int mt = 0; mt < 7; ++mt){
      const float* ap = px + (size_t)(mt*16 + l15)*1536 + koff;
      f4v lo = *(const f4v*)ap;
      f4v hi = *(const f4v*)(ap + 4);
      s8v A;
      A[0] = (short)f2b(lo[0]); A[1] = (short)f2b(lo[1]);
      A[2] = (short)f2b(lo[2]); A[3] = (short)f2b(lo[3]);
      A[4] = (short)f2b(hi[0]); A[5] = (short)f2b(hi[1]);
      A[6] = (short)f2b(hi[2]); A[7] = (short)f2b(hi[3]);
      #pragma unroll
      for (int nt = 0; nt < 4; ++nt)
        acc[mt][nt] = mfma16(A, Bf[nt], acc[mt][nt]);
    }
  }
  #pragma unroll
  for (int nt = 0; nt < 4; ++nt){
    int col = colb + nt*16 + l15;
    #pragma unroll
    for (int mt = 0; mt < 7; ++mt)
      #pragma unroll
      for (int v = 0; v < 4; ++v){
        int row = mt*16 + lhi*4 + v;
        if (row < B) atomicAdd(&h[row*2048 + col], acc[mt][nt][v]);
      }
  }
}

// ========== m2 + bias1/relu on the fly + sigmoid ==========
__global__ __launch_bounds__(192) void k_m2(const float* __restrict__ h, const float* __restrict__ bm1,
                                            const float* __restrict__ w_m2, const float* __restrict__ b_m2,
                                            float* __restrict__ out){
  int b = blockIdx.x, col = threadIdx.x;
  if (col >= 157) return;
  float acc = b_m2[col];
  const float* hb = h + (size_t)b*2048;
  for (int k = 0; k < 2048; ++k)
    acc += fmaxf(hb[k] + bm1[k], 0.f) * w_m2[(size_t)k*157 + col];
  out[b*157 + col] = 1.f/(1.f + expf(-acc));
}

extern "C" void kernel_launch(void* const* d_in, const int* in_sizes, int n_in,
                              void* d_out, int out_size, void* d_ws, size_t ws_size,
                              hipStream_t stream){
  const float* features   = (const float*)d_in[0];
  const float* union_feat = (const float*)d_in[1];
  const float* masks      = (const float*)d_in[2];
  const float* w_union    = (const float*)d_in[3];
  const float* b_union    = (const float*)d_in[4];
  const float* w_c1       = (const float*)d_in[5];
  const float* b_c1       = (const float*)d_in[6];
  const float* g_bn1      = (const float*)d_in[7];
  const float* be_bn1     = (const float*)d_in[8];
  const float* w_c2       = (const float*)d_in[9];
  const float* b_c2       = (const float*)d_in[10];
  const float* g_bn2      = (const float*)d_in[11];
  const float* be_bn2     = (const float*)d_in[12];
  const float* w_subj     = (const float*)d_in[13];
  const float* b_subj     = (const float*)d_in[14];
  const float* w_obj      = (const float*)d_in[15];
  const float* b_obj      = (const float*)d_in[16];
  const float* w_vr       = (const float*)d_in[17];
  const float* b_vr       = (const float*)d_in[18];
  const float* w_m1       = (const float*)d_in[19];
  const float* b_m1       = (const float*)d_in[20];
  const float* w_m2       = (const float*)d_in[21];
  const float* b_m2       = (const float*)d_in[22];
  const int* pair_idx     = (const int*)d_in[23];
  const int* im_idx       = (const int*)d_in[24];
  float* out = (float*)d_out;
  const int P = in_sizes[24];
  const int B = out_size/157;

  char* ws = (char*)d_ws;
  size_t off = 0;
  auto alloc = [&](size_t bytes)->size_t{ size_t o = off; off += (bytes + 255) & ~(size_t)255; return o; };
  // zero-region (one memset): stats | segr | px | h
  size_t o_stats= alloc(3072);
  size_t o_segr = alloc((size_t)B*256*49*4);
  size_t o_px   = alloc((size_t)112*1536*4);
  size_t o_h    = alloc((size_t)B*2048*4);
  size_t zero_end = off;
  size_t o_muT  = alloc((size_t)B*49*1024*2);
  size_t o_spool= alloc((size_t)P*49*128*2);
  size_t o_w1t  = alloc(128*128*2);
  size_t o_w2t  = alloc(9*256*128*2);
  size_t o_wuT  = alloc(256*1024*2);
  size_t o_wvrT = alloc((size_t)512*12544*2);
  size_t o_wm1T = alloc((size_t)2048*1536*2);
  size_t o_tbf  = alloc((size_t)112*12544*2);
  (void)ws_size; (void)n_in;

  float* stats1 = (float*)(ws + o_stats);
  float* stats2 = stats1 + 256;
  u16*   muT    = (u16*)(ws + o_muT);
  u16*   spool  = (u16*)(ws + o_spool);
  u16*   w1t    = (u16*)(ws + o_w1t);
  u16*   w2t    = (u16*)(ws + o_w2t);
  u16*   wuT    = (u16*)(ws + o_wuT);
  u16*   wvrT   = (u16*)(ws + o_wvrT);
  u16*   wm1T   = (u16*)(ws + o_wm1T);
  float* segr   = (float*)(ws + o_segr);
  u16*   tbf    = (u16*)(ws + o_tbf);
  float* px     = (float*)(ws + o_px);
  float* h      = (float*)(ws + o_h);

  hipMemsetAsync(ws, 0, zero_end, stream);

  dim3 blk(256);
  k_pre<<<6376, blk, 0, stream>>>(union_feat, features, pair_idx, im_idx,
                                  w_c1, w_c2, w_union, w_vr, w_m1,
                                  w_subj, b_subj, w_obj, b_obj,
                                  muT, w1t, w2t, wuT, wvrT, wm1T, px, P);
  k_conv1<<<P, blk, 0, stream>>>(masks, w1t, b_c1, stats1, spool);
  k_conv2<<<dim3(B, 5), dim3(512), 0, stream>>>(spool, w2t, b_c2, g_bn1, be_bn1, stats1, im_idx,
                                                segr, stats2, P, 1.f/((float)P*196.f));
  k_combine<<<B, blk, 0, stream>>>(muT, wuT, b_union, segr, stats2, g_bn2, be_bn2, im_idx,
                                   tbf, P, 1.f/((float)P*49.f));
  k_vr<<<dim3(2, 28), blk, 0, stream>>>(tbf, wvrT, b_vr, px, B);
  k_m1<<<dim3(8, 4), blk, 0, stream>>>(px, wm1T, h, B);
  k_m2<<<B, dim3(192), 0, stream>>>(h, b_m1, w_m2, b_m2, out);
}

// Round 4
// 1423.990 us; speedup vs baseline: 1.1518x; 1.0064x over previous
//
#include <hip/hip_runtime.h>

typedef unsigned short u16;
typedef unsigned int   u32;
typedef short s8v __attribute__((ext_vector_type(8)));   // 8 x bf16 (4 VGPR) MFMA operand
typedef float f4v __attribute__((ext_vector_type(4)));   // MFMA accumulator

#define DEV __device__ __forceinline__

DEV u16 f2b(float f){                      // f32 -> bf16, round-to-nearest-even
  u32 x = __builtin_bit_cast(u32, f);
  u32 r = x + 0x7fffu + ((x >> 16) & 1u);
  return (u16)(r >> 16);
}
DEV float b2f(u16 u){ u32 x = ((u32)u) << 16; return __builtin_bit_cast(float, x); }
DEV f4v mfma16(s8v a, s8v b, f4v c){ return __builtin_amdgcn_mfma_f32_16x16x32_bf16(a, b, c, 0, 0, 0); }

// binary-search segment [s0,s1) of image b in sorted im_idx
DEV void segrange(const int* __restrict__ im, int P, int b, int& s0, int& s1){
  int lo = 0, hi = P;
  while (lo < hi){ int m = (lo + hi) >> 1; if (im[m] < b) lo = m + 1; else hi = m; }
  s0 = lo;
  int lo2 = lo; hi = P;
  while (lo2 < hi){ int m = (lo2 + hi) >> 1; if (im[m] < b + 1) lo2 = m + 1; else hi = m; }
  s1 = lo2;
}

DEV void transpose_body(const float* __restrict__ src, u16* __restrict__ dst,
                        int R, int C, int rb, int cb, int t, float* tile){
  int r0 = rb << 6, c0 = cb << 6;
  for (int i = t; i < 4096; i += 256){
    int rl = i >> 6, cl = i & 63;
    tile[rl*65 + cl] = src[(size_t)(r0 + rl)*C + c0 + cl];
  }
  __syncthreads();
  for (int i = t; i < 4096; i += 256){
    int cl = i >> 6, rl = i & 63;
    dst[(size_t)(c0 + cl)*R + r0 + rl] = f2b(tile[rl*65 + cl]);
  }
}

// ================= k_pre: ALL input-only streaming work (no heavy per-block compute) ========
// [0,1600): union segment-mean -> muT   [1600,1800): feature segment-mean -> pfbf (bf16)
// [1800,1864): w1t  [1864,3016): w2t  [3016,4040): wuT  [4040,5608): wvrT  [5608,6376): wm1T
// [6376,6632): w_subj^T -> wsoT[0:512]   [6632,6888): w_obj^T -> wsoT[512:1024]
__global__ __launch_bounds__(256) void k_pre(
    const float* __restrict__ uf, const float* __restrict__ feat,
    const int* __restrict__ pidx, const int* __restrict__ im_idx,
    const float* __restrict__ w_c1, const float* __restrict__ w_c2, const float* __restrict__ w_u,
    const float* __restrict__ w_vr, const float* __restrict__ w_m1,
    const float* __restrict__ w_subj, const float* __restrict__ w_obj,
    u16* __restrict__ muT, u16* __restrict__ w1t, u16* __restrict__ w2t,
    u16* __restrict__ wuT, u16* __restrict__ wvrT, u16* __restrict__ wm1T,
    u16* __restrict__ wsoT, u16* __restrict__ pfbf, int P){
  __shared__ float smem[4160];
  int bid = blockIdx.x, t = threadIdx.x;
  if (bid < 1600){
    int b = bid >> 4, icb = bid & 15;
    int s0, s1; segrange(im_idx, P, b, s0, s1);
    float inv = 1.f / fmaxf((float)(s1 - s0), 1.f);
    f4v a0 = {}, a1 = {}, a2 = {}, a3 = {};
    int p = s0;
    for (; p + 1 < s1; p += 2){
      const f4v* x = (const f4v*)(uf + (size_t)p*50176 + icb*3136);
      const f4v* y = (const f4v*)(uf + (size_t)(p+1)*50176 + icb*3136);
      a0 += x[t] + y[t]; a1 += x[t+256] + y[t+256]; a2 += x[t+512] + y[t+512];
      if (t < 16) a3 += x[t+768] + y[t+768];
    }
    if (p < s1){
      const f4v* x = (const f4v*)(uf + (size_t)p*50176 + icb*3136);
      a0 += x[t]; a1 += x[t+256]; a2 += x[t+512];
      if (t < 16) a3 += x[t+768];
    }
    *(f4v*)&smem[4*t] = a0;
    *(f4v*)&smem[4*(t+256)] = a1;
    *(f4v*)&smem[4*(t+512)] = a2;
    if (t < 16) *(f4v*)&smem[4*(t+768)] = a3;
    __syncthreads();
    for (int o = t; o < 3136; o += 256){
      int pix = o >> 6, ics = o & 63;
      muT[(size_t)(b*49 + pix)*1024 + (icb<<6) + ics] = f2b(smem[ics*49 + pix]*inv);
    }
  } else if (bid < 1800){
    int i = bid - 1600; int s = i/100, b = i - s*100;
    int s0, s1; segrange(im_idx, P, b, s0, s1);
    float inv = 1.f / fmaxf((float)(s1 - s0), 1.f);
    f4v a0 = {}, a1 = {};
    for (int p = s0; p < s1; ++p){
      int row = pidx[p*2 + s];
      const f4v* src = (const f4v*)(feat + (size_t)row*2048);
      a0 += src[t]; a1 += src[t+256];
    }
    u16* dst = pfbf + (size_t)(s*100 + b)*2048;
    #pragma unroll
    for (int j = 0; j < 4; ++j){
      dst[4*t + j]        = f2b(a0[j]*inv);
      dst[1024 + 4*t + j] = f2b(a1[j]*inv);
    }
  } else if (bid < 1864){
    int i = (bid - 1800)*256 + t;          // [128 oc][128 k]
    int k = i & 127;
    w1t[i] = f2b(k < 98 ? w_c1[(i>>7)*98 + k] : 0.f);
  } else if (bid < 3016){
    int i = (bid - 1864)*256 + t;          // [9 tap][256 oc][128 ic]
    int tap = i >> 15, r = i & 32767;
    w2t[i] = f2b(w_c2[((r>>7)*128 + (r & 127))*9 + tap]);
  } else if (bid < 4040){
    int i = (bid - 3016)*256 + t;
    wuT[i] = f2b(w_u[i]);
  } else if (bid < 5608){
    int idx = bid - 4040;                  // 196*8
    transpose_body(w_vr, wvrT, 12544, 512, idx >> 3, idx & 7, t, smem);
  } else if (bid < 6376){
    int idx = bid - 5608;                  // 24*32
    transpose_body(w_m1, wm1T, 1536, 2048, idx >> 5, idx & 31, t, smem);
  } else if (bid < 6632){
    int idx = bid - 6376;                  // 32*8
    transpose_body(w_subj, wsoT, 2048, 512, idx >> 3, idx & 7, t, smem);
  } else {
    int idx = bid - 6632;                  // 32*8
    transpose_body(w_obj, wsoT + (size_t)512*2048, 2048, 512, idx >> 3, idx & 7, t, smem);
  }
}

// ========== conv1 (7x7 s2 p3, 2->128): hoisted-k im2col, reg-resident B, fused stats + u16 maxpool ==========
__global__ __launch_bounds__(256) void k_conv1(const float* __restrict__ masks, const u16* __restrict__ w1t,
                                               const float* __restrict__ b1,
                                               float* __restrict__ stats1, u16* __restrict__ spool){
  __shared__ u16 in_bf[2178];       // [2][33][33] zero-padded input, bf16
  __shared__ u16 a2col[28288];      // [208 m][136 k]; reused as s1n[128 oc][196 pix]
  int p = blockIdx.x, t = threadIdx.x;
  int lane = t & 63, w = t >> 6;
  int l15 = lane & 15, lhi = lane >> 4;
  s8v Bf[4][2];                     // whole B panel in regs (w1t is 32KB, L2-hot)
  #pragma unroll
  for (int kst = 0; kst < 4; ++kst){
    Bf[kst][0] = *(const s8v*)&w1t[(w*32 + l15)*128 + kst*32 + lhi*8];
    Bf[kst][1] = *(const s8v*)&w1t[(w*32 + 16 + l15)*128 + kst*32 + lhi*8];
  }
  for (int i = t; i < 1089; i += 256) ((u32*)in_bf)[i] = 0;
  for (int i = t; i < 768; i += 256){            // zero only pad rows 196..207, k<128
    int r = i >> 6, c = i & 63;
    ((u32*)&a2col[(196 + r)*136])[c] = 0;
  }
  __syncthreads();
  for (int e = t; e < 1458; e += 256){
    int c = e >= 729; int r = e - c*729;
    int rr = r/27, cc = r - rr*27;
    in_bf[c*1089 + (rr + 3)*33 + cc + 3] = f2b(masks[(size_t)p*1458 + e]);
  }
  __syncthreads();
  {                                  // im2col with per-thread-constant k
    int k = t & 127;
    bool valid = k < 98;
    int ic = k >= 49; int r = k - ic*49;
    int ky = r/7, kx = r - ky*7;
    int sbase = ic*1089 + ky*33 + kx;
    for (int pix = t >> 7; pix < 196; pix += 2){
      int oy = pix/14, ox = pix - oy*14;
      a2col[pix*136 + k] = valid ? in_bf[sbase + oy*66 + ox*2] : (u16)0;
    }
  }
  __syncthreads();
  f4v acc[13][2] = {};
  #pragma unroll
  for (int kst = 0; kst < 4; ++kst){
    int koff = kst*32 + lhi*8;
    #pragma unroll
    for (int mt = 0; mt < 13; ++mt){
      s8v A = *(const s8v*)&a2col[(mt*16 + l15)*136 + koff];
      acc[mt][0] = mfma16(A, Bf[kst][0], acc[mt][0]);
      acc[mt][1] = mfma16(A, Bf[kst][1], acc[mt][1]);
    }
  }
  __syncthreads();                       // all waves done reading a2col before s1n overwrite
  u16* s1n = a2col;                      // [128 oc][196 pix], PRE-BN relu (BN applied in conv2; maxpool∘BN commutes)
  int ocb = w*32;
  float ss[2] = {0,0}, qq[2] = {0,0};
  #pragma unroll
  for (int n = 0; n < 2; ++n){
    int oc = ocb + n*16 + l15;
    float bias = b1[oc];
    #pragma unroll
    for (int mt = 0; mt < 13; ++mt)
      #pragma unroll
      for (int v = 0; v < 4; ++v){
        int pix = mt*16 + lhi*4 + v;
        if (pix < 196){
          float r = fmaxf(acc[mt][n][v] + bias, 0.f);
          ss[n] += r; qq[n] += r*r;
          s1n[oc*196 + pix] = f2b(r);
        }
      }
  }
  #pragma unroll
  for (int n = 0; n < 2; ++n){
    float s = ss[n], q = qq[n];
    s += __shfl_xor(s, 16); s += __shfl_xor(s, 32);
    q += __shfl_xor(q, 16); q += __shfl_xor(q, 32);
    if (lane < 16){
      atomicAdd(&stats1[ocb + n*16 + lane], s);
      atomicAdd(&stats1[128 + ocb + n*16 + lane], q);
    }
  }
  __syncthreads();
  for (int j = t; j < 6272; j += 256){   // maxpool 3x3 s2 p1, u16-compare (relu => bits monotone)
    int oc = j & 127, pp = j >> 7;
    int poy = pp/7, pox = pp - poy*7;
    u32 m = 0;
    #pragma unroll
    for (int dy = 0; dy < 3; ++dy){
      int iy = poy*2 - 1 + dy;
      if (iy < 0 || iy > 13) continue;
      #pragma unroll
      for (int dx = 0; dx < 3; ++dx){
        int ix = pox*2 - 1 + dx;
        if (ix < 0 || ix > 13) continue;
        u32 v = s1n[oc*196 + iy*14 + ix];
        m = v > m ? v : m;
      }
    }
    spool[((size_t)p*49 + pp)*128 + oc] = (u16)m;
  }
}

// ========== conv2 (3x3 s1 p1, 128->256): oc-split x2 across blocks (halves per-CU LDS re-reads) ==========
__global__ __launch_bounds__(256) void k_conv2(const u16* __restrict__ spool, const u16* __restrict__ w2t,
                                               const float* __restrict__ b2,
                                               const float* __restrict__ g1, const float* __restrict__ be1,
                                               const float* __restrict__ stats1, const int* __restrict__ im_idx,
                                               float* __restrict__ segr, float* __restrict__ stats2,
                                               int P, float invN1){
  __shared__ u16 inT[164*136];     // rows: ppix*2+pair (0..161), 162 = zero row; stride 136 u16
  __shared__ float sc1[128], sh1[128];
  int b = blockIdx.x, q = blockIdx.y, t = threadIdx.x;
  int lane = t & 63, w = t >> 6;
  int l15 = lane & 15, lhi = lane >> 4;
  {
    f4v z = {}; f4v* a4 = (f4v*)inT;
    for (int i = t; i < 2788; i += 256) a4[i] = z;
  }
  if (t < 128){                    // folded bnfin1
    float mean = stats1[t]*invN1;
    float var  = stats1[128 + t]*invN1 - mean*mean;
    float sc = g1[t]*rsqrtf(var + 1e-5f);
    sc1[t] = sc; sh1[t] = be1[t] - mean*sc;
  }
  int s0, s1; segrange(im_idx, P, b, s0, s1);
  int cnt = s1 - s0, chunk = (cnt + 4)/5;
  int p0 = s0 + q*chunk, p1 = min(p0 + chunk, s1);
  int ocb = blockIdx.z*128 + w*32;
  int pym[7], pxm[7], prm[7]; bool okm[7];
  #pragma unroll
  for (int mt = 0; mt < 7; ++mt){
    int row = mt*16 + l15;
    int pix = row >> 1; prm[mt] = row & 1;
    okm[mt] = pix < 49;
    pym[mt] = pix/7; pxm[mt] = pix - pym[mt]*7;
  }
  float bias[2];
  bias[0] = b2[ocb + l15]; bias[1] = b2[ocb + 16 + l15];
  f4v segacc[7][2] = {};
  float ssum[2] = {0,0}, ssq[2] = {0,0};
  for (int p = p0; p < p1; p += 2){
    __syncthreads();
    int hasB = (p + 1 < p1);
    for (int j = t; j < 6272; j += 256){
      int pp = j >= 3136;
      if (pp && !hasB) break;
      int i = j - pp*3136;
      u32 v = ((const u32*)(spool + (size_t)(p + pp)*6272))[i];
      int pix = i >> 6, icp = i & 63;
      float lo = b2f((u16)v)*sc1[icp*2]     + sh1[icp*2];
      float hi = b2f((u16)(v >> 16))*sc1[icp*2 + 1] + sh1[icp*2 + 1];
      int py = pix/7, pxx = pix - py*7;
      int row = ((py + 1)*9 + pxx + 1)*2 + pp;
      ((u32*)inT)[row*68 + icp] = (u32)f2b(lo) | ((u32)f2b(hi) << 16);
    }
    __syncthreads();
    f4v pacc[7][2] = {};
    #pragma unroll
    for (int tap = 0; tap < 9; ++tap){
      int dy = tap/3 - 1, dx = tap%3 - 1;
      int rowb[7];
      #pragma unroll
      for (int mt = 0; mt < 7; ++mt)
        rowb[mt] = okm[mt] ? (((pym[mt] + 1 + dy)*9 + pxm[mt] + 1 + dx)*2 + prm[mt])*136 : 162*136;
      s8v Bt[4][2];                      // batch all 8 B-frag loads -> one L2 latency per tap
      #pragma unroll
      for (int kst = 0; kst < 4; ++kst){
        int koff = kst*32 + lhi*8;
        Bt[kst][0] = *(const s8v*)&w2t[(size_t)(tap*256 + ocb + l15)*128 + koff];
        Bt[kst][1] = *(const s8v*)&w2t[(size_t)(tap*256 + ocb + 16 + l15)*128 + koff];
      }
      #pragma unroll
      for (int kst = 0; kst < 4; ++kst){
        int koff = kst*32 + lhi*8;
        #pragma unroll
        for (int mt = 0; mt < 7; ++mt){
          s8v A = *(const s8v*)&inT[rowb[mt] + koff];
          pacc[mt][0] = mfma16(A, Bt[kst][0], pacc[mt][0]);
          pacc[mt][1] = mfma16(A, Bt[kst][1], pacc[mt][1]);
        }
      }
    }
    #pragma unroll
    for (int n = 0; n < 2; ++n)
      #pragma unroll
      for (int mt = 0; mt < 7; ++mt)
        #pragma unroll
        for (int v = 0; v < 4; ++v){
          int row = mt*16 + lhi*4 + v;
          int pix = row >> 1, pr = row & 1;
          float r = fmaxf(pacc[mt][n][v] + bias[n], 0.f);
          r = (pix < 49 && (pr == 0 || hasB)) ? r : 0.f;
          segacc[mt][n][v] += r;
          ssum[n] += r; ssq[n] += r*r;
        }
  }
  #pragma unroll
  for (int n = 0; n < 2; ++n){
    int oc = ocb + n*16 + l15;
    #pragma unroll
    for (int mt = 0; mt < 7; ++mt){
      int pix0 = (mt*16 + lhi*4) >> 1;
      if (pix0 < 49)
        atomicAdd(&segr[(size_t)(b*256 + oc)*49 + pix0], segacc[mt][n][0] + segacc[mt][n][1]);
      if (pix0 + 1 < 49)
        atomicAdd(&segr[(size_t)(b*256 + oc)*49 + pix0 + 1], segacc[mt][n][2] + segacc[mt][n][3]);
    }
    float s = ssum[n], qd = ssq[n];
    s  += __shfl_xor(s, 16);  s  += __shfl_xor(s, 32);
    qd += __shfl_xor(qd, 16); qd += __shfl_xor(qd, 32);
    if (lane < 16){
      atomicAdd(&stats2[ocb + n*16 + lane], s);
      atomicAdd(&stats2[256 + ocb + n*16 + lane], qd);
    }
  }
}

// ========== combine: union 1x1 conv (pooled) + bn2(seg-mean relu2), folded bnfin2 -> tbf ==========
__global__ __launch_bounds__(256) void k_combine(const u16* __restrict__ muT, const u16* __restrict__ wuT,
                                                 const float* __restrict__ b_u, const float* __restrict__ segr,
                                                 const float* __restrict__ stats2,
                                                 const float* __restrict__ g2, const float* __restrict__ be2,
                                                 const int* __restrict__ im_idx, u16* __restrict__ tbf,
                                                 int P, float invN2){
  __shared__ float sc2[256], sh2[256];
  int b = blockIdx.x, t = threadIdx.x;
  int lane = t & 63, w = t >> 6;
  int l15 = lane & 15, lhi = lane >> 4;
  {
    float mean = stats2[t]*invN2;
    float var  = stats2[256 + t]*invN2 - mean*mean;
    float sc = g2[t]*rsqrtf(var + 1e-5f);
    sc2[t] = sc; sh2[t] = be2[t] - mean*sc;
  }
  __syncthreads();
  int s0, s1; segrange(im_idx, P, b, s0, s1);
  float inv = 1.f / fmaxf((float)(s1 - s0), 1.f);
  int ocb = w*64;
  const u16* arow[4];
  #pragma unroll
  for (int mt = 0; mt < 4; ++mt){
    int pix = mt*16 + l15;
    arow[mt] = muT + (size_t)(b*49 + (pix < 49 ? pix : 0))*1024;   // invalid rows discarded at store
  }
  f4v acc[4][4] = {};
  for (int kst = 0; kst < 32; ++kst){
    int koff = kst*32 + lhi*8;
    s8v Bf[4];
    #pragma unroll
    for (int nt = 0; nt < 4; ++nt)
      Bf[nt] = *(const s8v*)&wuT[(ocb + nt*16 + l15)*1024 + koff];
    #pragma unroll
    for (int mt = 0; mt < 4; ++mt){
      s8v A = *(const s8v*)&arow[mt][koff];
      #pragma unroll
      for (int nt = 0; nt < 4; ++nt)
        acc[mt][nt] = mfma16(A, Bf[nt], acc[mt][nt]);
    }
  }
  #pragma unroll
  for (int nt = 0; nt < 4; ++nt){
    int oc = ocb + nt*16 + l15;
    float bu = b_u[oc], sc = sc2[oc], sh = sh2[oc];
    #pragma unroll
    for (int mt = 0; mt < 4; ++mt)
      #pragma unroll
      for (int v = 0; v < 4; ++v){
        int pix = mt*16 + lhi*4 + v;
        if (pix < 49){
          float val = acc[mt][nt][v] + bu + sc*segr[(size_t)(b*256 + oc)*49 + pix]*inv + sh;
          tbf[(size_t)b*12544 + oc*49 + pix] = f2b(val);
        }
      }
  }
}

// ========== vr GEMM: [112,12544]@[12544,512], k-split, b_vr bias at kc==0, atomic into px cols 1024.. ==========
__global__ __launch_bounds__(256) void k_vr(const u16* __restrict__ tbf, const u16* __restrict__ wvrT,
                                            const float* __restrict__ b_vr, float* __restrict__ px, int B){
  int nb = blockIdx.x, kc = blockIdx.y, t = threadIdx.x;
  int lane = t & 63, w = t >> 6;
  int l15 = lane & 15, lhi = lane >> 4;
  int colb = nb*256 + w*64;
  int k0 = kc*448;
  f4v acc[7][4] = {};
  for (int kst = 0; kst < 14; ++kst){
    int koff = k0 + kst*32 + lhi*8;
    s8v Bf[4];
    #pragma unroll
    for (int nt = 0; nt < 4; ++nt)
      Bf[nt] = *(const s8v*)&wvrT[(size_t)(colb + nt*16 + l15)*12544 + koff];
    #pragma unroll
    for (int mt = 0; mt < 7; ++mt){
      s8v A = *(const s8v*)&tbf[(size_t)(mt*16 + l15)*12544 + koff];
      #pragma unroll
      for (int nt = 0; nt < 4; ++nt)
        acc[mt][nt] = mfma16(A, Bf[nt], acc[mt][nt]);
    }
  }
  #pragma unroll
  for (int nt = 0; nt < 4; ++nt){
    int col = colb + nt*16 + l15;
    float bias = (kc == 0) ? b_vr[col] : 0.f;
    #pragma unroll
    for (int mt = 0; mt < 7; ++mt)
      #pragma unroll
      for (int v = 0; v < 4; ++v){
        int row = mt*16 + lhi*4 + v;
        if (row < B) atomicAdd(&px[row*1536 + 1024 + col], acc[mt][nt][v] + bias);
      }
  }
}

// ========== subj/obj GEMM: [112,2048]@[2048,512] per s, k-split x4, atomics into px cols s*512.. ==========
__global__ __launch_bounds__(256) void k_so(const u16* __restrict__ pfbf, const u16* __restrict__ wsoT,
                                            const float* __restrict__ b_subj, const float* __restrict__ b_obj,
                                            float* __restrict__ px, int B){
  int nb = blockIdx.x, s = blockIdx.y, kc = blockIdx.z, t = threadIdx.x;
  int lane = t & 63, w = t >> 6;
  int l15 = lane & 15, lhi = lane >> 4;
  int colb = nb*256 + w*64;
  int k0 = kc*512;
  const float* bi = s ? b_obj : b_subj;
  f4v acc[7][4] = {};
  for (int kst = 0; kst < 16; ++kst){
    int koff = k0 + kst*32 + lhi*8;
    s8v Bf[4];
    #pragma unroll
    for (int nt = 0; nt < 4; ++nt)
      Bf[nt] = *(const s8v*)&wsoT[(size_t)(s*512 + colb + nt*16 + l15)*2048 + koff];
    #pragma unroll
    for (int mt = 0; mt < 7; ++mt){
      int row = mt*16 + l15; row = row < B ? row : 0;
      s8v A = *(const s8v*)&pfbf[(size_t)(s*100 + row)*2048 + koff];
      #pragma unroll
      for (int nt = 0; nt < 4; ++nt)
        acc[mt][nt] = mfma16(A, Bf[nt], acc[mt][nt]);
    }
  }
  #pragma unroll
  for (int nt = 0; nt < 4; ++nt){
    int col = colb + nt*16 + l15;
    float bias = (kc == 0) ? bi[col] : 0.f;
    #pragma unroll
    for (int mt = 0; mt < 7; ++mt)
      #pragma unroll
      for (int v = 0; v < 4; ++v){
        int row = mt*16 + lhi*4 + v;
        if (row < B) atomicAdd(&px[row*1536 + s*512 + col], acc[mt][nt][v] + bias);
      }
  }
}

// ========== MLP m1: [112,1536]@[1536,2048], k-split atomics; A = f32 px converted inline ==========
__global__ __launch_bounds__(256) void k_m1(const float* __restrict__ px, const u16* __restrict__ wm1T,
                                            float* __restrict__ h, int B){
  int nb = blockIdx.x, kc = blockIdx.y, t = threadIdx.x;
  int lane = t & 63, w = t >> 6;
  int l15 = lane & 15, lhi = lane >> 4;
  int colb = nb*256 + w*64;
  int k0 = kc*384;
  f4v acc[7][4] = {};
  for (int kst = 0; kst < 12; ++kst){
    int koff = k0 + kst*32 + lhi*8;
    s8v Bf[4];
    #pragma unroll
    for (int nt = 0; nt < 4; ++nt)
      Bf[nt] = *(const s8v*)&wm1T[(size_t)(colb + nt*16 + l15)*1536 + koff];
    #pragma unroll
    for (int mt = 0; mt < 7; ++mt){
      const float* ap = px + (size_t)(mt*16 + l15)*1536 + koff;
      f4v lo = *(const f4v*)ap;
      f4v hi = *(const f4v*)(ap + 4);
      s8v A;
      A[0] = (short)f2b(lo[0]); A[1] = (short)f2b(lo[1]);
      A[2] = (short)f2b(lo[2]); A[3] = (short)f2b(lo[3]);
      A[4] = (short)f2b(hi[0]); A[5] = (short)f2b(hi[1]);
      A[6] = (short)f2b(hi[2]); A[7] = (short)f2b(hi[3]);
      #pragma unroll
      for (int nt = 0; nt < 4; ++nt)
        acc[mt][nt] = mfma16(A, Bf[nt], acc[mt][nt]);
    }
  }
  #pragma unroll
  for (int nt = 0; nt < 4; ++nt){
    int col = colb + nt*16 + l15;
    #pragma unroll
    for (int mt = 0; mt < 7; ++mt)
      #pragma unroll
      for (int v = 0; v < 4; ++v){
        int row = mt*16 + lhi*4 + v;
        if (row < B) atomicAdd(&h[row*2048 + col], acc[mt][nt][v]);
      }
  }
}

// ========== m2 + bias1/relu on the fly + sigmoid ==========
__global__ __launch_bounds__(192) void k_m2(const float* __restrict__ h, const float* __restrict__ bm1,
                                            const float* __restrict__ w_m2, const float* __restrict__ b_m2,
                                            float* __restrict__ out){
  int b = blockIdx.x, col = threadIdx.x;
  if (col >= 157) return;
  float acc = b_m2[col];
  const float* hb = h + (size_t)b*2048;
  for (int k = 0; k < 2048; ++k)
    acc += fmaxf(hb[k] + bm1[k], 0.f) * w_m2[(size_t)k*157 + col];
  out[b*157 + col] = 1.f/(1.f + expf(-acc));
}

extern "C" void kernel_launch(void* const* d_in, const int* in_sizes, int n_in,
                              void* d_out, int out_size, void* d_ws, size_t ws_size,
                              hipStream_t stream){
  const float* features   = (const float*)d_in[0];
  const float* union_feat = (const float*)d_in[1];
  const float* masks      = (const float*)d_in[2];
  const float* w_union    = (const float*)d_in[3];
  const float* b_union    = (const float*)d_in[4];
  const float* w_c1       = (const float*)d_in[5];
  const float* b_c1       = (const float*)d_in[6];
  const float* g_bn1      = (const float*)d_in[7];
  const float* be_bn1     = (const float*)d_in[8];
  const float* w_c2       = (const float*)d_in[9];
  const float* b_c2       = (const float*)d_in[10];
  const float* g_bn2      = (const float*)d_in[11];
  const float* be_bn2     = (const float*)d_in[12];
  const float* w_subj     = (const float*)d_in[13];
  const float* b_subj     = (const float*)d_in[14];
  const float* w_obj      = (const float*)d_in[15];
  const float* b_obj      = (const float*)d_in[16];
  const float* w_vr       = (const float*)d_in[17];
  const float* b_vr       = (const float*)d_in[18];
  const float* w_m1       = (const float*)d_in[19];
  const float* b_m1       = (const float*)d_in[20];
  const float* w_m2       = (const float*)d_in[21];
  const float* b_m2       = (const float*)d_in[22];
  const int* pair_idx     = (const int*)d_in[23];
  const int* im_idx       = (const int*)d_in[24];
  float* out = (float*)d_out;
  const int P = in_sizes[24];
  const int B = out_size/157;

  char* ws = (char*)d_ws;
  size_t off = 0;
  auto alloc = [&](size_t bytes)->size_t{ size_t o = off; off += (bytes + 255) & ~(size_t)255; return o; };
  // zero-region (one memset): stats | segr | px | h
  size_t o_stats= alloc(3072);
  size_t o_segr = alloc((size_t)B*256*49*4);
  size_t o_px   = alloc((size_t)112*1536*4);
  size_t o_h    = alloc((size_t)B*2048*4);
  size_t zero_end = off;
  size_t o_muT  = alloc((size_t)B*49*1024*2);
  size_t o_spool= alloc((size_t)P*49*128*2);
  size_t o_w1t  = alloc(128*128*2);
  size_t o_w2t  = alloc(9*256*128*2);
  size_t o_wuT  = alloc(256*1024*2);
  size_t o_wvrT = alloc((size_t)512*12544*2);
  size_t o_wm1T = alloc((size_t)2048*1536*2);
  size_t o_wsoT = alloc((size_t)1024*2048*2);
  size_t o_pfbf = alloc((size_t)200*2048*2);
  size_t o_tbf  = alloc((size_t)112*12544*2);
  (void)ws_size; (void)n_in;

  float* stats1 = (float*)(ws + o_stats);
  float* stats2 = stats1 + 256;
  u16*   muT    = (u16*)(ws + o_muT);
  u16*   spool  = (u16*)(ws + o_spool);
  u16*   w1t    = (u16*)(ws + o_w1t);
  u16*   w2t    = (u16*)(ws + o_w2t);
  u16*   wuT    = (u16*)(ws + o_wuT);
  u16*   wvrT   = (u16*)(ws + o_wvrT);
  u16*   wm1T   = (u16*)(ws + o_wm1T);
  u16*   wsoT   = (u16*)(ws + o_wsoT);
  u16*   pfbf   = (u16*)(ws + o_pfbf);
  float* segr   = (float*)(ws + o_segr);
  u16*   tbf    = (u16*)(ws + o_tbf);
  float* px     = (float*)(ws + o_px);
  float* h      = (float*)(ws + o_h);

  hipMemsetAsync(ws, 0, zero_end, stream);

  dim3 blk(256);
  k_pre<<<6888, blk, 0, stream>>>(union_feat, features, pair_idx, im_idx,
                                  w_c1, w_c2, w_union, w_vr, w_m1,
                                  w_subj, w_obj,
                                  muT, w1t, w2t, wuT, wvrT, wm1T, wsoT, pfbf, P);
  k_conv1<<<P, blk, 0, stream>>>(masks, w1t, b_c1, stats1, spool);
  k_conv2<<<dim3(B, 5, 2), blk, 0, stream>>>(spool, w2t, b_c2, g_bn1, be_bn1, stats1, im_idx,
                                             segr, stats2, P, 1.f/((float)P*196.f));
  k_combine<<<B, blk, 0, stream>>>(muT, wuT, b_union, segr, stats2, g_bn2, be_bn2, im_idx,
                                   tbf, P, 1.f/((float)P*49.f));
  k_vr<<<dim3(2, 28), blk, 0, stream>>>(tbf, wvrT, b_vr, px, B);
  k_so<<<dim3(2, 2, 4), blk, 0, stream>>>(pfbf, wsoT, b_subj, b_obj, px, B);
  k_m1<<<dim3(8, 4), blk, 0, stream>>>(px, wm1T, h, B);
  k_m2<<<B, dim3(192), 0, stream>>>(h, b_m1, w_m2, b_m2, out);
}